// Round 12
// baseline (369.372 us; speedup 1.0000x reference)
//
#include <hip/hip_runtime.h>

// Poisson learning, split-fp16 MFMA:
//   prep: W*32 -> Whi/Wlo fp16; samples -> fp16
//   gemm1: R11: B-OPERAND DIRECT FROM GLOBAL (L2) -- LDS stages A only:
//          staging 32->16KB/subtile, LDS reads 96->64/CU-subtile (~900cy
//          < MFMA 1242cy -> MFMA-critical), ring 128->64KB -> 2 blocks/CU
//          (R8-proven TLP) with NO extra HBM traffic (R9's failure mode
//          avoided: B comes from L2, FETCH stays ~77MB). B frags are
//          volatile-asm global_load_dwordx4; counted ledger: issue
//          [B(s+1)x4, Astage(s+3)x2] per step -> vmcnt(12) pre-barrier
//          (A(s+1) resident), vmcnt(8) pre-MFMA (B(s) ready), lgkmcnt(2)
//          (A(s) ds_reads retired). Bit-identical data (LDS swizzle was
//          self-inverse). 256x128 tile, XCD-chunked map kept.
//   gemm2: R8 3-slot ring, 2 blocks/CU + R10 batch->XCD pinning.
//   rowstats/make_at: 4 rows/block ILP. make_db: split 128-block pair.
//   power iteration: fused iter_step (R6) + R10 batch->XCD pinning.

typedef _Float16 f16_t;
typedef f16_t f16x4 __attribute__((ext_vector_type(4)));
typedef f16_t f16x8 __attribute__((ext_vector_type(8)));
typedef float floatx4 __attribute__((ext_vector_type(4)));

__device__ __forceinline__ void async_copy16(const void* g, void* l) {
  __builtin_amdgcn_global_load_lds(
      (const __attribute__((address_space(1))) void*)g,
      (__attribute__((address_space(3))) void*)l, 16, 0, 0);
}

__device__ __forceinline__ f16_t hi_of(float x) { return (f16_t)x; }
__device__ __forceinline__ f16_t lo_of(float x, f16_t h) {
  return (f16_t)(x - (float)h);
}

// blocks [0,3072): W*32 -> hi/lo.  blocks [3072,27648): samples -> fp16
__global__ __launch_bounds__(256) void prep_kernel(
    const float* __restrict__ W, f16_t* __restrict__ Whi, f16_t* __restrict__ Wlo,
    const float* __restrict__ samples, f16_t* __restrict__ SampH)
{
  const int bx = blockIdx.x, tid = threadIdx.x;
  if (bx < 3072) {
    const int i = bx * 256 + tid;
    float4 v = ((const float4*)W)[i];
    v.x *= 32.f; v.y *= 32.f; v.z *= 32.f; v.w *= 32.f;
    f16x4 h, l;
    f16_t h0 = hi_of(v.x); h[0] = h0; l[0] = lo_of(v.x, h0);
    f16_t h1 = hi_of(v.y); h[1] = h1; l[1] = lo_of(v.y, h1);
    f16_t h2 = hi_of(v.z); h[2] = h2; l[2] = lo_of(v.z, h2);
    f16_t h3 = hi_of(v.w); h[3] = h3; l[3] = lo_of(v.w, h3);
    *(f16x4*)(Whi + (size_t)i * 4) = h;
    *(f16x4*)(Wlo + (size_t)i * 4) = l;
  } else {
    const int i = (bx - 3072) * 256 + tid;
    const float4 v = ((const float4*)samples)[i];
    f16x4 h;
    h[0] = (f16_t)v.x; h[1] = (f16_t)v.y; h[2] = (f16_t)v.z; h[3] = (f16_t)v.w;
    *(f16x4*)(SampH + (size_t)i * 4) = h;
  }
}

// fragment set for one BK=32 subtile of gemm1: 8 A frags + 2x2 B frags
struct Frags {
  f16x8 a[8];
  f16x8 bh0, bh1, bl0, bl1;
};

// volatile-asm ds_read_b128: issue order pinned; WE own the lgkmcnt guard.
#define DSR(dst_, addr_, OFFSTR_) \
  asm volatile("ds_read_b128 %0, %1 offset:" OFFSTR_ : "=v"(dst_) : "v"(addr_))

// volatile-asm global_load_dwordx4 (B frags direct from L2); WE own vmcnt.
#define GLD(dst_, ptr_) \
  asm volatile("global_load_dwordx4 %0, %1, off" : "=v"(dst_) : "v"(ptr_))

// ---------------------------------------------------------------------------
// gemm1 (R11): C = A @ (Bh+Bl)^T, split-store. 256x128 tile, 8 waves.
// A: BK=32, 4-slot x 16KB LDS ring (64KB -> 2 blocks/CU), gload_lds with
// pre-swizzled source + swizzled ds_read (conflict-free, R1-verified).
// B: per-wave frags loaded DIRECTLY from global (L2) via asm dwordx4.
// Counted waits per half-step: vmcnt(12) [A(s+1) in LDS], lgkmcnt(2)
// [A(s) ds_reads retired], vmcnt(8) [B(s) regs ready]. XCD-chunked map.
// ---------------------------------------------------------------------------
__global__ __launch_bounds__(512, 2) void gemm1_pipe(
    const f16_t* __restrict__ Ag,
    const f16_t* __restrict__ BhG, const f16_t* __restrict__ BlG,
    const float* __restrict__ bias,
    f16_t* __restrict__ Chi, f16_t* __restrict__ Clo,
    int N, int K, float cscale)
{
  __shared__ __align__(16) char smem[65536];  // 4 slots x 16384 B (A only)

  const int tid = threadIdx.x;
  const int lane = tid & 63;
  const int wave = tid >> 6;        // 0..7
  const int wm = wave >> 2;         // 0..1  -> 128-row half
  const int wn = wave & 3;          // 0..3  -> 32-col quarter
  // XCD-chunked swizzle: XCD k owns a 4(n) x 8(m) tile rectangle.
  const int bid0 = blockIdx.y * 8 + blockIdx.x;
  const int xk = bid0 & 7, xj = bid0 >> 3;
  const int m0 = ((xk >> 1) * 8 + (xj >> 2)) * 256;
  const int n0 = ((xk & 1) * 4 + (xj & 3)) * 128;
  const int fr = lane & 15;
  const int lch = lane >> 4;        // logical 16B chunk (k-group)

  // --- A staging sources (pre-swizzled global addr; LDS dest linear) ---
  const int gA0 = tid;              // A granules: tid, tid+512  (1024 x 16B)
  const int gA1 = tid + 512;
  const int rA0 = gA0 >> 2, lcA0 = (gA0 & 3) ^ ((rA0 >> 1) & 3);
  const int rA1 = gA1 >> 2, lcA1 = (gA1 & 3) ^ ((rA1 >> 1) & 3);
  const f16_t* aSrc0 = Ag + (size_t)(m0 + rA0) * K + lcA0 * 8;
  const f16_t* aSrc1 = Ag + (size_t)(m0 + rA1) * K + lcA1 * 8;
  char* ldsA0 = smem + gA0 * 16;
  char* ldsA1 = smem + gA1 * 16;

  // --- B fragment global sources (per-lane; no LDS, no swizzle needed) ---
  const f16_t* bh0Src = BhG + (size_t)(n0 + wn * 32 + fr) * K + lch * 8;
  const f16_t* bh1Src = BhG + (size_t)(n0 + wn * 32 + 16 + fr) * K + lch * 8;
  const f16_t* bl0Src = BlG + (size_t)(n0 + wn * 32 + fr) * K + lch * 8;
  const f16_t* bl1Src = BlG + (size_t)(n0 + wn * 32 + 16 + fr) * K + lch * 8;

  // --- swizzled A read offsets; per-slot LDS addresses (named scalars) ---
  const int swz = (lch ^ ((fr >> 1) & 3)) * 16;
  const int aoff = (wm * 128 + fr) * 64 + swz;
  const unsigned ldsBase =
      (unsigned)(size_t)(__attribute__((address_space(3))) char*)smem;
  const unsigned aA0 = ldsBase + (unsigned)aoff;
  const unsigned aA1 = aA0 + 16384u;
  const unsigned aA2 = aA0 + 32768u;
  const unsigned aA3 = aA0 + 49152u;

  floatx4 acc[8][2] = {};
  const int NS = K >> 5;            // 96 subtiles (multiple of 4)

#define STAGEA(SS_, SLOT_)                                    \
  do {                                                        \
    int ss = (SS_); if (ss >= NS) ss -= NS;                   \
    const int k0 = ss * 32;                                   \
    async_copy16(aSrc0 + k0, ldsA0 + (SLOT_) * 16384);        \
    async_copy16(aSrc1 + k0, ldsA1 + (SLOT_) * 16384);        \
  } while (0)

#define LOADB(SS_, FRD_)                                      \
  do {                                                        \
    int sb = (SS_); if (sb >= NS) sb -= NS;                   \
    const int kb = sb * 32;                                   \
    GLD(FRD_.bh0, bh0Src + kb);                               \
    GLD(FRD_.bh1, bh1Src + kb);                               \
    GLD(FRD_.bl0, bl0Src + kb);                               \
    GLD(FRD_.bl1, bl1Src + kb);                               \
  } while (0)

#define MFMA8(F_, P_)                                                                                               \
  do {                                                                                                              \
    acc[2*(P_)][0]   = __builtin_amdgcn_mfma_f32_16x16x32_f16((F_).a[2*(P_)],   (F_).bh0, acc[2*(P_)][0],   0,0,0); \
    acc[2*(P_)][1]   = __builtin_amdgcn_mfma_f32_16x16x32_f16((F_).a[2*(P_)],   (F_).bh1, acc[2*(P_)][1],   0,0,0); \
    acc[2*(P_)+1][0] = __builtin_amdgcn_mfma_f32_16x16x32_f16((F_).a[2*(P_)+1], (F_).bh0, acc[2*(P_)+1][0], 0,0,0); \
    acc[2*(P_)+1][1] = __builtin_amdgcn_mfma_f32_16x16x32_f16((F_).a[2*(P_)+1], (F_).bh1, acc[2*(P_)+1][1], 0,0,0); \
    acc[2*(P_)][0]   = __builtin_amdgcn_mfma_f32_16x16x32_f16((F_).a[2*(P_)],   (F_).bl0, acc[2*(P_)][0],   0,0,0); \
    acc[2*(P_)][1]   = __builtin_amdgcn_mfma_f32_16x16x32_f16((F_).a[2*(P_)],   (F_).bl1, acc[2*(P_)][1],   0,0,0); \
    acc[2*(P_)+1][0] = __builtin_amdgcn_mfma_f32_16x16x32_f16((F_).a[2*(P_)+1], (F_).bl0, acc[2*(P_)+1][0], 0,0,0); \
    acc[2*(P_)+1][1] = __builtin_amdgcn_mfma_f32_16x16x32_f16((F_).a[2*(P_)+1], (F_).bl1, acc[2*(P_)+1][1], 0,0,0); \
  } while (0)

#define SB0 __builtin_amdgcn_sched_barrier(0)

// Half-step at subtile s (SPRE_ = s+3): load B(s+1) regs, stage A(s+3),
// sync A(s+1) into LDS, then 4x{2 A ds_reads(s+1) | 8 MFMA(s)}.
// Ledger (issue window [Astage(s+1),B(s),Astage(s+2),B(s+1),Astage(s+3)]):
//   vmcnt(12) -> Astage(s+1) drained; vmcnt(8) -> B(s) drained;
//   lgkmcnt(2) -> A(s)'s 8 ds_reads retired (in-order DS).
#define HALF(SPRE_, SLOTPRE_, ARD_, FRD_, FMM_)                  \
  do {                                                           \
    LOADB((SPRE_) - 2, FRD_);                                    \
    STAGEA(SPRE_, SLOTPRE_);                                     \
    asm volatile("s_waitcnt vmcnt(12)" ::: "memory");            \
    __builtin_amdgcn_s_barrier();                                \
    DSR(FRD_.a[0], ARD_, "0");                                   \
    DSR(FRD_.a[1], ARD_, "1024");                                \
    SB0;                                                         \
    asm volatile("s_waitcnt lgkmcnt(2) vmcnt(8)" ::: "memory");  \
    SB0;                                                         \
    __builtin_amdgcn_s_setprio(1);                               \
    MFMA8(FMM_, 0);                                              \
    __builtin_amdgcn_s_setprio(0);                               \
    SB0;                                                         \
    DSR(FRD_.a[2], ARD_, "2048");                                \
    DSR(FRD_.a[3], ARD_, "3072");                                \
    SB0;                                                         \
    __builtin_amdgcn_s_setprio(1);                               \
    MFMA8(FMM_, 1);                                              \
    __builtin_amdgcn_s_setprio(0);                               \
    SB0;                                                         \
    DSR(FRD_.a[4], ARD_, "4096");                                \
    DSR(FRD_.a[5], ARD_, "5120");                                \
    SB0;                                                         \
    __builtin_amdgcn_s_setprio(1);                               \
    MFMA8(FMM_, 2);                                              \
    __builtin_amdgcn_s_setprio(0);                               \
    SB0;                                                         \
    DSR(FRD_.a[6], ARD_, "6144");                                \
    DSR(FRD_.a[7], ARD_, "7168");                                \
    SB0;                                                         \
    __builtin_amdgcn_s_setprio(1);                               \
    MFMA8(FMM_, 3);                                              \
    __builtin_amdgcn_s_setprio(0);                               \
    SB0;                                                         \
  } while (0)

  Frags f0, f1;

  // prologue (issue order matches steady state: A0, A1, B0, A2):
  STAGEA(0, 0);
  STAGEA(1, 1);
  LOADB(0, f0);
  STAGEA(2, 2);
  asm volatile("s_waitcnt vmcnt(8)" ::: "memory");   // A(0) resident
  __builtin_amdgcn_s_barrier();
  DSR(f0.a[0], aA0, "0");
  DSR(f0.a[1], aA0, "1024");
  DSR(f0.a[2], aA0, "2048");
  DSR(f0.a[3], aA0, "3072");
  DSR(f0.a[4], aA0, "4096");
  DSR(f0.a[5], aA0, "5120");
  DSR(f0.a[6], aA0, "6144");
  DSR(f0.a[7], aA0, "7168");
  SB0;

  for (int s = 0; s < NS; s += 4) {
    HALF(s + 3, 3, aA1, f1, f0);   // B(s+1), A-stage(s+3); read A(s+1); mfma s
    HALF(s + 4, 0, aA2, f0, f1);
    HALF(s + 5, 1, aA3, f1, f0);
    HALF(s + 6, 2, aA0, f0, f1);
  }
  asm volatile("s_waitcnt vmcnt(0)" ::: "memory");
#undef HALF
#undef STAGEA
#undef LOADB
#undef MFMA8

  // epilogue: v*cscale + bias, split-store hi/lo
  const int mr = (lane >> 4) * 4;
#pragma unroll
  for (int j = 0; j < 2; ++j) {
    const int n = n0 + wn * 32 + j * 16 + fr;
    const float bj = bias[n];
#pragma unroll
    for (int i = 0; i < 8; ++i) {
#pragma unroll
      for (int r = 0; r < 4; ++r) {
        const int m = m0 + wm * 128 + i * 16 + mr + r;
        float v = acc[i][j][r] * cscale + bj;
        f16_t h = hi_of(v);
        Chi[(size_t)m * N + n] = h;
        Clo[(size_t)m * N + n] = lo_of(v, h);
      }
    }
  }
}

// fragment set for one BK=32 granule of gemm2: 4 A + 4 Bh + 4 Bl
struct Frags2 {
  f16x8 a[4];
  f16x8 bh[4];
  f16x8 bl[4];
};

// ---------------------------------------------------------------------------
// gemm2_pipe: G = S S^T - 1e5 I, triangular tiles + mirror (R8, verified).
// 3-slot x 24KB ring (72KB LDS) -> 2 blocks/CU. R10: flat 288-block grid,
// batch = bid&7 pins each batch's 36 blocks to one XCD (S 4MB fits L2).
// ---------------------------------------------------------------------------
__global__ __launch_bounds__(256, 2) void gemm2_pipe(
    const f16_t* __restrict__ Sh, const f16_t* __restrict__ Sl,
    float* __restrict__ Gf)
{
  const int K = 1024, N = 1024;
  const int batch = blockIdx.x & 7;          // XCD = linear bid % 8 (m09)
  const long long bo = (long long)batch * (1024LL * 1024);
  const f16_t* Ahi = Sh + bo;
  const f16_t* Bhi = Sh + bo;
  const f16_t* Blo = Sl + bo;
  float* Cf = Gf + bo;

  __shared__ __align__(16) char smem[73728];  // 3 slots x 24576 B

  const int tid = threadIdx.x;
  const int lane = tid & 63;
  const int wave = tid >> 6;       // 0..3
  const int wm = wave >> 1, wn = wave & 1;

  // triangular pair mapping: idx -> (i >= j)
  int idx = blockIdx.x >> 3, ti = 0, accu = 0;
  while (accu + ti + 1 <= idx) { accu += ti + 1; ++ti; }
  const int m0 = ti * 128;
  const int n0 = (idx - accu) * 128;

  const int fr = lane & 15;
  const int lch = lane >> 4;

  // staging: per thread 6 x 16B granule-chunks (A 2, Bh 2, Bl 2)
  const int gA0 = tid, gA1 = tid + 256;
  const int rA0 = gA0 >> 2, cA0 = (gA0 & 3) ^ ((rA0 >> 1) & 3);
  const int rA1 = gA1 >> 2, cA1 = (gA1 & 3) ^ ((rA1 >> 1) & 3);
  const f16_t* aSr0 = Ahi + (size_t)(m0 + rA0) * K + cA0 * 8;
  const f16_t* aSr1 = Ahi + (size_t)(m0 + rA1) * K + cA1 * 8;
  const f16_t* hSr0 = Bhi + (size_t)(n0 + rA0) * K + cA0 * 8;
  const f16_t* hSr1 = Bhi + (size_t)(n0 + rA1) * K + cA1 * 8;
  const f16_t* lSr0 = Blo + (size_t)(n0 + rA0) * K + cA0 * 8;
  const f16_t* lSr1 = Blo + (size_t)(n0 + rA1) * K + cA1 * 8;
  char* dA0 = smem + gA0 * 16;
  char* dA1 = smem + gA1 * 16;
  char* dH0 = smem + 8192 + gA0 * 16;
  char* dH1 = smem + 8192 + gA1 * 16;
  char* dL0 = smem + 16384 + gA0 * 16;
  char* dL1 = smem + 16384 + gA1 * 16;

  // swizzled read offsets; per-slot LDS addresses
  const int swz16 = (lch ^ ((fr >> 1) & 3)) * 16;
  const int aoff = (wm * 64 + fr) * 64 + swz16;
  const int boff = (wn * 64 + fr) * 64 + swz16;
  const unsigned ldsBase =
      (unsigned)(size_t)(__attribute__((address_space(3))) char*)smem;
  const unsigned aT0 = ldsBase + (unsigned)aoff;
  const unsigned aT1 = aT0 + 24576u;
  const unsigned aT2 = aT0 + 49152u;
  const unsigned bT0 = ldsBase + 8192u + (unsigned)boff;
  const unsigned bT1 = bT0 + 24576u;
  const unsigned bT2 = bT0 + 49152u;

  floatx4 acc[4][4] = {};
  const int NS = 32;

#define STAGE2(SS_, SLOT_)                                    \
  do {                                                        \
    int ss = (SS_); if (ss >= NS) ss -= NS;                   \
    const int k0 = ss * 32;                                   \
    async_copy16(aSr0 + k0, dA0 + (SLOT_) * 24576);           \
    async_copy16(aSr1 + k0, dA1 + (SLOT_) * 24576);           \
    async_copy16(hSr0 + k0, dH0 + (SLOT_) * 24576);           \
    async_copy16(hSr1 + k0, dH1 + (SLOT_) * 24576);           \
    async_copy16(lSr0 + k0, dL0 + (SLOT_) * 24576);           \
    async_copy16(lSr1 + k0, dL1 + (SLOT_) * 24576);           \
  } while (0)

#define MFMA8_2(F_, P_)                                                                              \
  do {                                                                                               \
    acc[0][P_] = __builtin_amdgcn_mfma_f32_16x16x32_f16((F_).a[0], (F_).bh[P_], acc[0][P_], 0,0,0);  \
    acc[1][P_] = __builtin_amdgcn_mfma_f32_16x16x32_f16((F_).a[1], (F_).bh[P_], acc[1][P_], 0,0,0);  \
    acc[2][P_] = __builtin_amdgcn_mfma_f32_16x16x32_f16((F_).a[2], (F_).bh[P_], acc[2][P_], 0,0,0);  \
    acc[3][P_] = __builtin_amdgcn_mfma_f32_16x16x32_f16((F_).a[3], (F_).bh[P_], acc[3][P_], 0,0,0);  \
    acc[0][P_] = __builtin_amdgcn_mfma_f32_16x16x32_f16((F_).a[0], (F_).bl[P_], acc[0][P_], 0,0,0);  \
    acc[1][P_] = __builtin_amdgcn_mfma_f32_16x16x32_f16((F_).a[1], (F_).bl[P_], acc[1][P_], 0,0,0);  \
    acc[2][P_] = __builtin_amdgcn_mfma_f32_16x16x32_f16((F_).a[2], (F_).bl[P_], acc[2][P_], 0,0,0);  \
    acc[3][P_] = __builtin_amdgcn_mfma_f32_16x16x32_f16((F_).a[3], (F_).bl[P_], acc[3][P_], 0,0,0);  \
  } while (0)

#define SB0 __builtin_amdgcn_sched_barrier(0)

#define GR3(SPRE_, SLOTPRE_, ARD_, BRD_, FRD_, FMM_)             \
  do {                                                           \
    STAGE2(SPRE_, SLOTPRE_);                                     \
    asm volatile("s_waitcnt vmcnt(6)" ::: "memory");             \
    __builtin_amdgcn_s_barrier();                                \
    DSR(FRD_.bh[0], BRD_, "0");                                  \
    DSR(FRD_.bh[1], BRD_, "1024");                               \
    DSR(FRD_.bh[2], BRD_, "2048");                               \
    SB0;                                                         \
    asm volatile("s_waitcnt lgkmcnt(3)" ::: "memory");           \
    SB0;                                                         \
    __builtin_amdgcn_s_setprio(1);                               \
    MFMA8_2(FMM_, 0);                                            \
    __builtin_amdgcn_s_setprio(0);                               \
    SB0;                                                         \
    DSR(FRD_.bh[3], BRD_, "3072");                               \
    DSR(FRD_.bl[0], BRD_, "8192");                               \
    DSR(FRD_.bl[1], BRD_, "9216");                               \
    SB0;                                                         \
    __builtin_amdgcn_s_setprio(1);                               \
    MFMA8_2(FMM_, 1);                                            \
    __builtin_amdgcn_s_setprio(0);                               \
    SB0;                                                         \
    DSR(FRD_.bl[2], BRD_, "10240");                              \
    DSR(FRD_.bl[3], BRD_, "11264");                              \
    DSR(FRD_.a[0], ARD_, "0");                                   \
    SB0;                                                         \
    __builtin_amdgcn_s_setprio(1);                               \
    MFMA8_2(FMM_, 2);                                            \
    __builtin_amdgcn_s_setprio(0);                               \
    SB0;                                                         \
    DSR(FRD_.a[1], ARD_, "1024");                                \
    DSR(FRD_.a[2], ARD_, "2048");                                \
    DSR(FRD_.a[3], ARD_, "3072");                                \
    SB0;                                                         \
    __builtin_amdgcn_s_setprio(1);                               \
    MFMA8_2(FMM_, 3);                                            \
    __builtin_amdgcn_s_setprio(0);                               \
    SB0;                                                         \
  } while (0)

  Frags2 f0, f1;

  // prologue: stage granules 0,1; read frags(0) from slot 0
  STAGE2(0, 0); STAGE2(1, 1);
  asm volatile("s_waitcnt vmcnt(6)" ::: "memory");   // granule 0 landed
  __builtin_amdgcn_s_barrier();
  DSR(f0.bh[0], bT0, "0");
  DSR(f0.bh[1], bT0, "1024");
  DSR(f0.bh[2], bT0, "2048");
  DSR(f0.bh[3], bT0, "3072");
  DSR(f0.bl[0], bT0, "8192");
  DSR(f0.bl[1], bT0, "9216");
  DSR(f0.bl[2], bT0, "10240");
  DSR(f0.bl[3], bT0, "11264");
  DSR(f0.a[0], aT0, "0");
  DSR(f0.a[1], aT0, "1024");
  DSR(f0.a[2], aT0, "2048");
  DSR(f0.a[3], aT0, "3072");
  SB0;

  // main loop: granules 0..29 (period-6 slot/frag pattern, 5 iters)
  for (int s = 0; s < 30; s += 6) {
    GR3(s + 2, 2, aT1, bT1, f1, f0);   // g=s+0: read s+1(slot1), mfma s
    GR3(s + 3, 0, aT2, bT2, f0, f1);   // g=s+1: read s+2(slot2), mfma s+1
    GR3(s + 4, 1, aT0, bT0, f1, f0);   // g=s+2: read s+3(slot0), mfma s+2
    GR3(s + 5, 2, aT1, bT1, f0, f1);   // g=s+3: read s+4(slot1), mfma s+3
    GR3(s + 6, 0, aT2, bT2, f1, f0);   // g=s+4: read s+5(slot2), mfma s+4
    GR3(s + 7, 1, aT0, bT0, f0, f1);   // g=s+5: read s+6(slot0), mfma s+5
  }
  // epilogue: granule 30 in f0 (read at g=29); granule 31 staged (slot 1)
  asm volatile("s_waitcnt vmcnt(0)" ::: "memory");
  __builtin_amdgcn_s_barrier();
  DSR(f1.bh[0], bT1, "0");
  DSR(f1.bh[1], bT1, "1024");
  DSR(f1.bh[2], bT1, "2048");
  DSR(f1.bh[3], bT1, "3072");
  DSR(f1.bl[0], bT1, "8192");
  DSR(f1.bl[1], bT1, "9216");
  DSR(f1.bl[2], bT1, "10240");
  DSR(f1.bl[3], bT1, "11264");
  DSR(f1.a[0], aT1, "0");
  DSR(f1.a[1], aT1, "1024");
  DSR(f1.a[2], aT1, "2048");
  DSR(f1.a[3], aT1, "3072");
  SB0;
  asm volatile("s_waitcnt lgkmcnt(12)" ::: "memory");  // granule 30 reads done
  SB0;
  __builtin_amdgcn_s_setprio(1);
  MFMA8_2(f0, 0); MFMA8_2(f0, 1); MFMA8_2(f0, 2); MFMA8_2(f0, 3);
  __builtin_amdgcn_s_setprio(0);
  SB0;
  asm volatile("s_waitcnt lgkmcnt(0)" ::: "memory");
  SB0;
  __builtin_amdgcn_s_setprio(1);
  MFMA8_2(f1, 0); MFMA8_2(f1, 1); MFMA8_2(f1, 2); MFMA8_2(f1, 3);
  __builtin_amdgcn_s_setprio(0);
#undef GR3
#undef MFMA8_2
#undef STAGE2

  // epilogue: C write (-1e5 diag), then mirror for off-diag tiles
  const int mr = (lane >> 4) * 4;
#pragma unroll
  for (int j = 0; j < 4; ++j) {
    const int n = n0 + wn * 64 + j * 16 + fr;
#pragma unroll
    for (int i = 0; i < 4; ++i) {
#pragma unroll
      for (int r = 0; r < 4; ++r) {
        const int m = m0 + wm * 64 + i * 16 + mr + r;
        float v = acc[i][j][r];
        if (m == n) v -= 1e5f;
        Cf[(size_t)m * N + n] = v;
      }
    }
  }

  if (m0 != n0) {
    float* T = (float*)smem;            // 128 x (stride 36) fp32 = 18432 B
#pragma unroll
    for (int mc = 0; mc < 4; ++mc) {    // 32-wide m-local chunks
      __syncthreads();
      if (wm == (mc >> 1)) {
        const int ibase = (mc & 1) * 2;
#pragma unroll
        for (int di = 0; di < 2; ++di) {
#pragma unroll
          for (int j = 0; j < 4; ++j) {
            const int nl = wn * 64 + j * 16 + fr;       // local col
#pragma unroll
            for (int r = 0; r < 4; ++r) {
              const int mloc = di * 16 + mr + r;        // within chunk
              T[nl * 36 + mloc] = acc[ibase + di][j][r];
            }
          }
        }
      }
      __syncthreads();
      const int row = tid >> 1, half = tid & 1;
      const float* src = &T[row * 36 + half * 16];
      float* dst = Cf + (size_t)(n0 + row) * N + m0 + mc * 32 + half * 16;
#pragma unroll
      for (int q = 0; q < 16; ++q) dst[q] = src[q];
    }
  }
}

// per-row max and 1/sum(exp(g-max)) of G; 4 rows per block (ILP)
__global__ __launch_bounds__(256) void rowstats_kernel(
    const float* __restrict__ G, float* __restrict__ mx, float* __restrict__ inv)
{
  __shared__ float redm[4][4], reds[4][4], mxsh[4];
  const int tid = threadIdx.x;
  const int r0 = blockIdx.x * 4;
  const float* g = G + (size_t)r0 * 1024;
  const float4 v0 = ((const float4*)g)[tid];
  const float4 v1 = ((const float4*)(g + 1024))[tid];
  const float4 v2 = ((const float4*)(g + 2048))[tid];
  const float4 v3 = ((const float4*)(g + 3072))[tid];

  float m0 = fmaxf(fmaxf(v0.x, v0.y), fmaxf(v0.z, v0.w));
  float m1 = fmaxf(fmaxf(v1.x, v1.y), fmaxf(v1.z, v1.w));
  float m2 = fmaxf(fmaxf(v2.x, v2.y), fmaxf(v2.z, v2.w));
  float m3 = fmaxf(fmaxf(v3.x, v3.y), fmaxf(v3.z, v3.w));
#pragma unroll
  for (int off = 32; off > 0; off >>= 1) {
    m0 = fmaxf(m0, __shfl_down(m0, off));
    m1 = fmaxf(m1, __shfl_down(m1, off));
    m2 = fmaxf(m2, __shfl_down(m2, off));
    m3 = fmaxf(m3, __shfl_down(m3, off));
  }
  if ((tid & 63) == 0) {
    redm[0][tid >> 6] = m0; redm[1][tid >> 6] = m1;
    redm[2][tid >> 6] = m2; redm[3][tid >> 6] = m3;
  }
  __syncthreads();
  if (tid < 4)
    mxsh[tid] = fmaxf(fmaxf(redm[tid][0], redm[tid][1]),
                      fmaxf(redm[tid][2], redm[tid][3]));
  __syncthreads();
  const float M0 = mxsh[0], M1 = mxsh[1], M2 = mxsh[2], M3 = mxsh[3];

  float s0 = __expf(v0.x - M0) + __expf(v0.y - M0) + __expf(v0.z - M0) + __expf(v0.w - M0);
  float s1 = __expf(v1.x - M1) + __expf(v1.y - M1) + __expf(v1.z - M1) + __expf(v1.w - M1);
  float s2 = __expf(v2.x - M2) + __expf(v2.y - M2) + __expf(v2.z - M2) + __expf(v2.w - M2);
  float s3 = __expf(v3.x - M3) + __expf(v3.y - M3) + __expf(v3.z - M3) + __expf(v3.w - M3);
#pragma unroll
  for (int off = 32; off > 0; off >>= 1) {
    s0 += __shfl_down(s0, off);
    s1 += __shfl_down(s1, off);
    s2 += __shfl_down(s2, off);
    s3 += __shfl_down(s3, off);
  }
  if ((tid & 63) == 0) {
    reds[0][tid >> 6] = s0; reds[1][tid >> 6] = s1;
    reds[2][tid >> 6] = s2; reds[3][tid >> 6] = s3;
  }
  __syncthreads();
  if (tid < 4) {
    mx[r0 + tid] = mxsh[tid];
    inv[r0 + tid] = 1.0f /
        (reds[tid][0] + reds[tid][1] + reds[tid][2] + reds[tid][3]);
  }
}

// At[l][m] = exp(G[l][m] - mx[m]) * inv[m]; 4 rows per block (ILP)
__global__ __launch_bounds__(256) void make_at_kernel(
    const float* __restrict__ G, const float* __restrict__ mx,
    const float* __restrict__ inv, f16_t* __restrict__ At)
{
  const int r0 = blockIdx.x * 4;
  const int b = r0 >> 10;
  const int tid = threadIdx.x;
  const float4 m = ((const float4*)(mx + b * 1024))[tid];
  const float4 iv = ((const float4*)(inv + b * 1024))[tid];
#pragma unroll
  for (int k = 0; k < 4; ++k) {
    const float4 g = ((const float4*)(G + (size_t)(r0 + k) * 1024))[tid];
    f16x4 o;
    o[0] = (f16_t)(__expf(g.x - m.x) * iv.x);
    o[1] = (f16_t)(__expf(g.y - m.y) * iv.y);
    o[2] = (f16_t)(__expf(g.z - m.z) * iv.z);
    o[3] = (f16_t)(__expf(g.w - m.w) * iv.w);
    *(f16x4*)(At + (size_t)(r0 + k) * 1024 + tid * 4) = o;
  }
}

// ---------------------------------------------------------------------------
// make_db split (R8): 128 blocks each. See R8 notes.
// ---------------------------------------------------------------------------
__global__ __launch_bounds__(256) void db_stats(
    const float* __restrict__ sup, float* __restrict__ colpart,
    float* __restrict__ totalpart)
{
  const int b = blockIdx.x >> 4, chunk = blockIdx.x & 15;
  const int tid = threadIdx.x;
  const int r = tid >> 2, q = tid & 3;
  const float* s = sup + ((size_t)b * 1024 + chunk * 64 + r) * 64 + q * 16;
  const float4 x0 = ((const float4*)s)[0];
  const float4 x1 = ((const float4*)s)[1];
  const float4 x2 = ((const float4*)s)[2];
  const float4 x3 = ((const float4*)s)[3];

  float rs = (x0.x + x0.y + x0.z + x0.w) + (x1.x + x1.y + x1.z + x1.w) +
             (x2.x + x2.y + x2.z + x2.w) + (x3.x + x3.y + x3.z + x3.w);
  rs += __shfl_xor(rs, 1);
  rs += __shfl_xor(rs, 2);
  const float rh = (rs > 0.5f) ? 1.f : 0.f;

  __shared__ float colp[64];
  __shared__ float tp[4];
  if (tid < 64) colp[tid] = 0.f;
  __syncthreads();
  atomicAdd(&colp[q * 16 + 0], x0.x);  atomicAdd(&colp[q * 16 + 1], x0.y);
  atomicAdd(&colp[q * 16 + 2], x0.z);  atomicAdd(&colp[q * 16 + 3], x0.w);
  atomicAdd(&colp[q * 16 + 4], x1.x);  atomicAdd(&colp[q * 16 + 5], x1.y);
  atomicAdd(&colp[q * 16 + 6], x1.z);  atomicAdd(&colp[q * 16 + 7], x1.w);
  atomicAdd(&colp[q * 16 + 8], x2.x);  atomicAdd(&colp[q * 16 + 9], x2.y);
  atomicAdd(&colp[q * 16 + 10], x2.z); atomicAdd(&colp[q * 16 + 11], x2.w);
  atomicAdd(&colp[q * 16 + 12], x3.x); atomicAdd(&colp[q * 16 + 13], x3.y);
  atomicAdd(&colp[q * 16 + 14], x3.z); atomicAdd(&colp[q * 16 + 15], x3.w);

  float ts = (q == 0) ? rh : 0.f;
#pragma unroll
  for (int off = 32; off > 0; off >>= 1) ts += __shfl_down(ts, off);
  if ((tid & 63) == 0) tp[tid >> 6] = ts;
  __syncthreads();
  if (tid < 64) colpart[((size_t)b * 16 + chunk) * 64 + tid] = colp[tid];
  if (tid == 0) totalpart[b * 16 + chunk] = tp[0] + tp[1] + tp[2] + tp[3];
}

__global__ __launch_bounds__(256) void db_apply(
    const float* __restrict__ sup, const float* __restrict__ colpart,
    const float* __restrict__ totalpart,
    float* __restrict__ Db, f16_t* __restrict__ DbT)
{
  const int b = blockIdx.x >> 4, chunk = blockIdx.x & 15;
  const int tid = threadIdx.x;
  const int r = tid >> 2, q = tid & 3;

  __shared__ float avgsh[64];
  __shared__ float totsh;
  __shared__ f16_t DbTs[64 * 72];

  float a = 0.f;
  if (tid < 64) {
#pragma unroll
    for (int c = 0; c < 16; ++c) a += colpart[((size_t)b * 16 + c) * 64 + tid];
  }
  if (tid == 0) {
    float tt = 0.f;
#pragma unroll
    for (int c = 0; c < 16; ++c) tt += totalpart[b * 16 + c];
    totsh = tt;
  }
  __syncthreads();
  if (tid < 64) avgsh[tid] = a / totsh;
  __syncthreads();

  const size_t rowoff = ((size_t)b * 1024 + chunk * 64 + r) * 64 + q * 16;
  const float* s = sup + rowoff;
  float4 x0 = ((const float4*)s)[0];
  float4 x1 = ((const float4*)s)[1];
  float4 x2 = ((const float4*)s)[2];
  float4 x3 = ((const float4*)s)[3];

  float rs = (x0.x + x0.y + x0.z + x0.w) + (x1.x + x1.y + x1.z + x1.w) +
             (x2.x + x2.y + x2.z + x2.w) + (x3.x + x3.y + x3.z + x3.w);
  rs += __shfl_xor(rs, 1);
  rs += __shfl_xor(rs, 2);
  const float rh = (rs > 0.5f) ? 1.f : 0.f;

  const int nb = q * 16;
  x0.x = (x0.x - avgsh[nb + 0]) * rh;  x0.y = (x0.y - avgsh[nb + 1]) * rh;
  x0.z = (x0.z - avgsh[nb + 2]) * rh;  x0.w = (x0.w - avgsh[nb + 3]) * rh;
  x1.x = (x1.x - avgsh[nb + 4]) * rh;  x1.y = (x1.y - avgsh[nb + 5]) * rh;
  x1.z = (x1.z - avgsh[nb + 6]) * rh;  x1.w = (x1.w - avgsh[nb + 7]) * rh;
  x2.x = (x2.x - avgsh[nb + 8]) * rh;  x2.y = (x2.y - avgsh[nb + 9]) * rh;
  x2.z = (x2.z - avgsh[nb + 10]) * rh; x2.w = (x2.w - avgsh[nb + 11]) * rh;
  x3.x = (x3.x - avgsh[nb + 12]) * rh; x3.y = (x3.y - avgsh[nb + 13]) * rh;
  x3.z = (x3.z - avgsh[nb + 14]) * rh; x3.w = (x3.w - avgsh[nb + 15]) * rh;

  float* d = Db + rowoff;
  ((float4*)d)[0] = x0; ((float4*)d)[1] = x1;
  ((float4*)d)[2] = x2; ((float4*)d)[3] = x3;

  DbTs[(nb + 0) * 72 + r] = (f16_t)x0.x;  DbTs[(nb + 1) * 72 + r] = (f16_t)x0.y;
  DbTs[(nb + 2) * 72 + r] = (f16_t)x0.z;  DbTs[(nb + 3) * 72 + r] = (f16_t)x0.w;
  DbTs[(nb + 4) * 72 + r] = (f16_t)x1.x;  DbTs[(nb + 5) * 72 + r] = (f16_t)x1.y;
  DbTs[(nb + 6) * 72 + r] = (f16_t)x1.z;  DbTs[(nb + 7) * 72 + r] = (f16_t)x1.w;
  DbTs[(nb + 8) * 72 + r] = (f16_t)x2.x;  DbTs[(nb + 9) * 72 + r] = (f16_t)x2.y;
  DbTs[(nb + 10) * 72 + r] = (f16_t)x2.z; DbTs[(nb + 11) * 72 + r] = (f16_t)x2.w;
  DbTs[(nb + 12) * 72 + r] = (f16_t)x3.x; DbTs[(nb + 13) * 72 + r] = (f16_t)x3.y;
  DbTs[(nb + 14) * 72 + r] = (f16_t)x3.z; DbTs[(nb + 15) * 72 + r] = (f16_t)x3.w;
  __syncthreads();

  // write DbT[n][chunk*64 + seg*16 ..): 16 f16 per thread, coalesced
  const int n = tid >> 2, seg = tid & 3;
  const f16_t* src = &DbTs[n * 72 + seg * 16];
  f16_t* dst = DbT + ((size_t)b * 64 + n) * 1024 + chunk * 64 + seg * 16;
  *(f16x8*)dst = *(const f16x8*)src;
  *(f16x8*)(dst + 8) = *(const f16x8*)(src + 8);
}

// ---------------------------------------------------------------------------
// Fused power-iteration step (R6): 256 blocks, 4 waves, private dbuf LDS
// per wave, reduce in old ks order -> bit-identical. R10: flat grid with
// batch = bid&7 -> batch's At (2MB) pinned to one XCD L2.
// ---------------------------------------------------------------------------
template <int PRED, int FINAL>
__global__ __launch_bounds__(256) void iter_step(
    const f16_t* __restrict__ At, const f16_t* __restrict__ UT,
    const float* __restrict__ Db, const float* __restrict__ Pred,
    f16_t* __restrict__ UTn, float* __restrict__ OutF)
{
  const int L = 1024, Nn = 64;
  const int b = blockIdx.x & 7, l0 = (blockIdx.x >> 3) * 32;
  At += (size_t)b * L * L;
  UT += (size_t)b * Nn * L;

  __shared__ __align__(16) char smem[131072];

  const int tid = threadIdx.x;
  const int lane = tid & 63;
  const int wave = tid >> 6;
  const int fr = lane & 15;
  const int lch = lane >> 4;
  const int mwb = wave * 256;       // wave's m-range base

  int g_, rw_, sc_;
  g_ = lane;        rw_ = g_ >> 3; sc_ = (g_ & 7) ^ (rw_ & 7);
  const f16_t* aS0 = At + (size_t)(l0 + rw_) * L + mwb + sc_ * 8;
  g_ = lane + 64;   rw_ = g_ >> 3; sc_ = (g_ & 7) ^ (rw_ & 7);
  const f16_t* aS1 = At + (size_t)(l0 + rw_) * L + mwb + sc_ * 8;
  g_ = lane + 128;  rw_ = g_ >> 3; sc_ = (g_ & 7) ^ (rw_ & 7);
  const f16_t* aS2 = At + (size_t)(l0 + rw_) * L + mwb + sc_ * 8;
  g_ = lane + 192;  rw_ = g_ >> 3; sc_ = (g_ & 7) ^ (rw_ & 7);
  const f16_t* aS3 = At + (size_t)(l0 + rw_) * L + mwb + sc_ * 8;
  g_ = lane;        rw_ = g_ >> 3; sc_ = (g_ & 7) ^ (rw_ & 7);
  const f16_t* uS0 = UT + (size_t)rw_ * L + mwb + sc_ * 8;
  g_ = lane + 64;   rw_ = g_ >> 3; sc_ = (g_ & 7) ^ (rw_ & 7);
  const f16_t* uS1 = UT + (size_t)rw_ * L + mwb + sc_ * 8;
  g_ = lane + 128;  rw_ = g_ >> 3; sc_ = (g_ & 7) ^ (rw_ & 7);
  const f16_t* uS2 = UT + (size_t)rw_ * L + mwb + sc_ * 8;
  g_ = lane + 192;  rw_ = g_ >> 3; sc_ = (g_ & 7) ^ (rw_ & 7);
  const f16_t* uS3 = UT + (size_t)rw_ * L + mwb + sc_ * 8;
  g_ = lane + 256;  rw_ = g_ >> 3; sc_ = (g_ & 7) ^ (rw_ & 7);
  const f16_t* uS4 = UT + (size_t)rw_ * L + mwb + sc_ * 8;
  g_ = lane + 320;  rw_ = g_ >> 3; sc_ = (g_ & 7) ^ (rw_ & 7);
  const f16_t* uS5 = UT + (size_t)rw_ * L + mwb + sc_ * 8;
  g_ = lane + 384;  rw_ = g_ >> 3; sc_ = (g_ & 7) ^ (rw_ & 7);
  const f16_t* uS6 = UT + (size_t)rw_ * L + mwb + sc_ * 8;
  g_ = lane + 448;  rw_ = g_ >> 3; sc_ = (g_ & 7) ^ (rw_ & 7);
  const f16_t* uS7 = UT + (size_t)rw_ * L + mwb + sc_ * 8;

  char* stA = smem + wave * 24576;          // buf c: +c*12288
  char* stU = stA + 4096;

  const int offK0 = fr * 128 + ((lch ^ (fr & 7)) * 16);
  const int offK1 = fr * 128 + (((4 + lch) ^ (fr & 7)) * 16);

  floatx4 acc[2][4] = {};

#define STG(M0_, BUF_)                                        \
  do {                                                        \
    char* dA = stA + (BUF_) * 12288;                          \
    char* dU = stU + (BUF_) * 12288;                          \
    async_copy16(aS0 + (M0_), dA + lane * 16);                \
    async_copy16(aS1 + (M0_), dA + 1024 + lane * 16);         \
    async_copy16(aS2 + (M0_), dA + 2048 + lane * 16);         \
    async_copy16(aS3 + (M0_), dA + 3072 + lane * 16);         \
    async_copy16(uS0 + (M0_), dU + lane * 16);                \
    async_copy16(uS1 + (M0_), dU + 1024 + lane * 16);         \
    async_copy16(uS2 + (M0_), dU + 2048 + lane * 16);         \
    async_copy16(uS3 + (M0_), dU + 3072 + lane * 16);         \
    async_copy16(uS4 + (M0_), dU + 4096 + lane * 16);         \
    async_copy16(uS5 + (M0_), dU + 5120 + lane * 16);         \
    async_copy16(uS6 + (M0_), dU + 6144 + lane * 16);         \
    async_copy16(uS7 + (M0_), dU + 7168 + lane * 16);         \
  } while (0)

#define LD8(b_, o_) (*(const f16x8*)((b_) + (o_)))
#define MM(A_, U_, C_) C_ = __builtin_amdgcn_mfma_f32_16x16x32_f16(A_, U_, C_, 0, 0, 0)

#define CHUNK(BUF_)                                                       \
  do {                                                                    \
    const char* cA = stA + (BUF_) * 12288;                                \
    const char* cU = stU + (BUF_) * 12288;                                \
    f16x8 a00 = LD8(cA, offK0), a01 = LD8(cA, offK1);                     \
    f16x8 a10 = LD8(cA, offK0 + 2048), a11 = LD8(cA, offK1 + 2048);       \
    f16x8 u00 = LD8(cU, offK0), u01 = LD8(cU, offK1);                     \
    f16x8 u10 = LD8(cU, offK0 + 2048), u11 = LD8(cU, offK1 + 2048);       \
    f16x8 u20 = LD8(cU, offK0 + 4096), u21 = LD8(cU, offK1 + 4096);       \
    f16x8 u30 = LD8(cU, offK0 + 6144), u31 = LD8(cU, offK1 + 6144);       \
    MM(a00, u00, acc[0][0]); MM(a00, u10, acc[0][1]);                     \
    MM(a00, u20, acc[0][2]); MM(a00, u30, acc[0][3]);                     \
    MM(a10, u00, acc[1][0]); MM(a10, u10, acc[1][1]);                     \
    MM(a10, u20, acc[1][2]); MM(a10, u30, acc[1][3]);                     \
    MM(a01, u01, acc[0][0]); MM(a01, u11, acc[0][1]);                     \
    MM(a01, u21, acc[0][2]); MM(a01, u31, acc[0][3]);                     \
    MM(a11, u01, acc[1][0]); MM(a11, u11, acc[1][1]);                     \
    MM(a11, u21, acc[1][2]); MM(a11, u31, acc[1][3]);                     \
  } while (0)

#define SB0 __builtin_amdgcn_sched_barrier(0)

  STG(0, 0);
  STG(64, 1);
  asm volatile("s_waitcnt vmcnt(12)" ::: "memory");
  SB0;
  CHUNK(0);
  SB0;
  STG(128, 0);
  asm volatile("s_waitcnt vmcnt(12)" ::: "memory");
  SB0;
  CHUNK(1);
  SB0;
  STG(192, 1);
  asm volatile("s_waitcnt vmcnt(12)" ::: "memory");
  SB0;
  CHUNK(0);
  SB0;
  asm volatile("s_waitcnt vmcnt(0)" ::: "memory");
  SB0;
  CHUNK(1);
#undef CHUNK
#undef STG

  // ---- reduce: write wave partials, then sum in old ks order ----
  float* P = (float*)(smem + 98304) + wave * 2048;    // 32x64 fp32
  const int mr = (lane >> 4) * 4;
#pragma unroll
  for (int li = 0; li < 2; ++li)
#pragma unroll
    for (int j = 0; j < 4; ++j)
#pragma unroll
      for (int r = 0; r < 4; ++r)
        P[(li * 16 + mr + r) * 64 + j * 16 + fr] = acc[li][j][r];
  __syncthreads();

  const float* P0 = (const float*)(smem + 98304);
  const size_t obase = ((size_t)b * L + l0) * Nn;
  f16_t* OutS = (f16_t*)smem;                         // 64 n x stride 40 f16
#pragma unroll
  for (int it = 0; it < 2; ++it) {
    const int e4 = it * 256 + tid;                    // 512 float4s
    const int l = e4 >> 4, n4 = (e4 & 15) * 4;
    const int eo = l * 64 + n4;
    float4 v = *(const float4*)(P0 + eo);
    const float4 p1 = *(const float4*)(P0 + 2048 + eo);
    const float4 p2 = *(const float4*)(P0 + 4096 + eo);
    const float4 p3 = *(const float4*)(P0 + 6144 + eo);
    v.x += p1.x; v.y += p1.y; v.z += p1.z; v.w += p1.w;
    v.x += p2.x; v.y += p2.y; v.z += p2.z; v.w += p2.w;
    v.x += p3.x; v.y += p3.y; v.z += p3.z; v.w += p3.w;
    const float4 d = *(const float4*)(Db + obase + eo);
    v.x += d.x; v.y += d.y; v.z += d.z; v.w += d.w;
    if (PRED) {
      const float4 p = *(const float4*)(Pred + obase + eo);
      v.x += p.x; v.y += p.y; v.z += p.z; v.w += p.w;
    }
    if (FINAL) {
      *(float4*)(OutF + obase + eo) = v;
    } else {
      OutS[(n4 + 0) * 40 + l] = (f16_t)v.x;
      OutS[(n4 + 1) * 40 + l] = (f16_t)v.y;
      OutS[(n4 + 2) * 40 + l] = (f16_t)v.z;
      OutS[(n4 + 3) * 40 + l] = (f16_t)v.w;
    }
  }
  if (!FINAL) {
    __syncthreads();
    f16_t* dst = UTn + (size_t)b * Nn * L + l0;
    const int n = tid >> 2, lc = (tid & 3) * 8;
    *(f16x8*)(dst + (size_t)n * L + lc) = *(const f16x8*)&OutS[n * 40 + lc];
  }
#undef SB0
#undef LD8
#undef MM
}

extern "C" void kernel_launch(void* const* d_in, const int* in_sizes, int n_in,
                              void* d_out, int out_size, void* d_ws, size_t ws_size,
                              hipStream_t stream) {
  const float* samples = (const float*)d_in[0];  // [8,1024,3072]
  const float* label   = (const float*)d_in[1];  // [8,1024,64]
  const float* predict = (const float*)d_in[2];  // [8,1024,64]
  const float* W       = (const float*)d_in[3];  // [1024,3072]
  const float* bproj   = (const float*)d_in[4];  // [1024]
  float* out = (float*)d_out;                    // [8,1024,64]

  char* ws = (char*)d_ws;
  // region A [0, 12.58 MB): Whi/Wlo during projection; small buffers after
  f16_t* Whi = (f16_t*)ws;
  f16_t* Wlo = (f16_t*)(ws + 6291456);
  float* mx  = (float*)ws;                       // after gemm1 (W dead)
  float* inv = (float*)(ws + 32768);
  float* Db  = (float*)(ws + 65536);             // 2 MB
  f16_t* DbT = (f16_t*)(ws + 65536 + 2097152);   // 1 MB
  f16_t* UTa = (f16_t*)(ws + 65536 + 3145728);   // 1 MB
  f16_t* UTb = (f16_t*)(ws + 65536 + 4194304);   // 1 MB
  float* colpart   = (float*)(ws + 5308416);     // 8x16x64 fp32 = 32 KB
  float* totalpart = (float*)(ws + 5308416 + 32768);  // 8x16 fp32
  // region B [12.58, 62.9 MB): SampH (50 MB) during gemm1; G (32 MB) after
  f16_t* SampH = (f16_t*)(ws + 12582912);
  float* G     = (float*)(ws + 12582912);
  // region C [62.9, 96.5 MB): Shi/Slo; At aliases Shi
  f16_t* Shi = (f16_t*)(ws + 62914560);
  f16_t* Slo = (f16_t*)(ws + 62914560 + 16777216);
  f16_t* At  = Shi;

  // 0) prep: W split + samples convert (fused)
  prep_kernel<<<dim3(27648), 256, 0, stream>>>(W, Whi, Wlo, samples, SampH);

  // 1) S = samples @ W^T + b; epilogue x(1/32)+bias, split-store hi/lo
  gemm1_pipe<<<dim3(8, 32), 512, 0, stream>>>(
      SampH, Whi, Wlo, bproj, Shi, Slo, 1024, 3072, 1.0f / 32.0f);

  // 2) G = S S^T - 1e5 I; flat 288 grid, batch = bid&7 -> XCD-pinned
  gemm2_pipe<<<dim3(288), 256, 0, stream>>>(Shi, Slo, G);

  // 3) row stats (4 rows/block), then At = softmax^T fp16 (4 rows/block)
  rowstats_kernel<<<2048, 256, 0, stream>>>(G, mx, inv);
  make_at_kernel<<<2048, 256, 0, stream>>>(G, mx, inv, At);

  // 4) Db fp32 + DbT fp16: stats partials + apply (128 blocks each)
  db_stats<<<128, 256, 0, stream>>>(label, colpart, totalpart);
  db_apply<<<128, 256, 0, stream>>>(label, colpart, totalpart, Db, DbT);

  // 5) power iteration: fused steps; flat 256 grid, batch = bid&7 XCD-pinned
  iter_step<0, 0><<<dim3(256), 256, 0, stream>>>(At, DbT, Db, nullptr, UTa, nullptr); // t=2
  iter_step<1, 0><<<dim3(256), 256, 0, stream>>>(At, UTa, Db, predict, UTb, nullptr); // t=3
  iter_step<0, 0><<<dim3(256), 256, 0, stream>>>(At, UTb, Db, nullptr, UTa, nullptr); // t=4
  iter_step<0, 0><<<dim3(256), 256, 0, stream>>>(At, UTa, Db, nullptr, UTb, nullptr); // t=5
  iter_step<0, 1><<<dim3(256), 256, 0, stream>>>(At, UTb, Db, nullptr, nullptr, out); // t=6
}

// Round 13
// 335.722 us; speedup vs baseline: 1.1002x; 1.1002x over previous
//
#include <hip/hip_runtime.h>

// Poisson learning, split-fp16 MFMA. R12 = REVERT to R10 (measured best,
// 342.7us):
//   gemm1: R8-verified 256x128 tile, 8 waves, BK=32 4-slot ring (128KB),
//          depth-3 vmcnt(8), asm ds_read frag dbuf, 4-phase {3 reads|8 MFMA},
//          XCD-chunked tile map. (R11's B-direct-from-L2 REGRESSED 96->131us:
//          per-lane B loads duplicated 2x across wm-pairs and serialized on
//          the vector-memory queue -> MfmaUtil 32%. LDS staging is the
//          bandwidth amplifier for operands shared by >=2 waves.)
//   gemm2: R8 3-slot ring, 2 blocks/CU + R10 batch->XCD pinning.
//   rowstats/make_at: 4 rows/block ILP. make_db: split 128-block pair.
//   power iteration: fused iter_step (R6) + R10 batch->XCD pinning.

typedef _Float16 f16_t;
typedef f16_t f16x4 __attribute__((ext_vector_type(4)));
typedef f16_t f16x8 __attribute__((ext_vector_type(8)));
typedef float floatx4 __attribute__((ext_vector_type(4)));

__device__ __forceinline__ void async_copy16(const void* g, void* l) {
  __builtin_amdgcn_global_load_lds(
      (const __attribute__((address_space(1))) void*)g,
      (__attribute__((address_space(3))) void*)l, 16, 0, 0);
}

__device__ __forceinline__ f16_t hi_of(float x) { return (f16_t)x; }
__device__ __forceinline__ f16_t lo_of(float x, f16_t h) {
  return (f16_t)(x - (float)h);
}

// blocks [0,3072): W*32 -> hi/lo.  blocks [3072,27648): samples -> fp16
__global__ __launch_bounds__(256) void prep_kernel(
    const float* __restrict__ W, f16_t* __restrict__ Whi, f16_t* __restrict__ Wlo,
    const float* __restrict__ samples, f16_t* __restrict__ SampH)
{
  const int bx = blockIdx.x, tid = threadIdx.x;
  if (bx < 3072) {
    const int i = bx * 256 + tid;
    float4 v = ((const float4*)W)[i];
    v.x *= 32.f; v.y *= 32.f; v.z *= 32.f; v.w *= 32.f;
    f16x4 h, l;
    f16_t h0 = hi_of(v.x); h[0] = h0; l[0] = lo_of(v.x, h0);
    f16_t h1 = hi_of(v.y); h[1] = h1; l[1] = lo_of(v.y, h1);
    f16_t h2 = hi_of(v.z); h[2] = h2; l[2] = lo_of(v.z, h2);
    f16_t h3 = hi_of(v.w); h[3] = h3; l[3] = lo_of(v.w, h3);
    *(f16x4*)(Whi + (size_t)i * 4) = h;
    *(f16x4*)(Wlo + (size_t)i * 4) = l;
  } else {
    const int i = (bx - 3072) * 256 + tid;
    const float4 v = ((const float4*)samples)[i];
    f16x4 h;
    h[0] = (f16_t)v.x; h[1] = (f16_t)v.y; h[2] = (f16_t)v.z; h[3] = (f16_t)v.w;
    *(f16x4*)(SampH + (size_t)i * 4) = h;
  }
}

// fragment set for one BK=32 subtile of gemm1: 8 A frags + 2x2 B frags
struct Frags {
  f16x8 a[8];
  f16x8 bh0, bh1, bl0, bl1;
};

// volatile-asm ds_read_b128: issue order pinned; WE own the lgkmcnt guard.
#define DSR(dst_, addr_, OFFSTR_) \
  asm volatile("ds_read_b128 %0, %1 offset:" OFFSTR_ : "=v"(dst_) : "v"(addr_))

__device__ __forceinline__ void read_frags_asm(unsigned sa, unsigned sb,
                                               Frags& f) {
  DSR(f.bh0, sb, "0");
  DSR(f.bh1, sb, "1024");
  DSR(f.bl0, sb, "8192");
  DSR(f.bl1, sb, "9216");
  DSR(f.a[0], sa, "0");
  DSR(f.a[1], sa, "1024");
  DSR(f.a[2], sa, "2048");
  DSR(f.a[3], sa, "3072");
  DSR(f.a[4], sa, "4096");
  DSR(f.a[5], sa, "5120");
  DSR(f.a[6], sa, "6144");
  DSR(f.a[7], sa, "7168");
}

// ---------------------------------------------------------------------------
// gemm1 (R8-verified): C = A @ (Bh+Bl)^T, split-store. 256x128 tile,
// 8 waves, BK=32 4-slot ring, depth-3 vmcnt(8), XCD-chunked tile map.
// ---------------------------------------------------------------------------
__global__ __launch_bounds__(512, 2) void gemm1_pipe(
    const f16_t* __restrict__ Ag,
    const f16_t* __restrict__ BhG, const f16_t* __restrict__ BlG,
    const float* __restrict__ bias,
    f16_t* __restrict__ Chi, f16_t* __restrict__ Clo,
    int N, int K, float cscale)
{
  __shared__ __align__(16) char smem[131072];  // 4 slots x 32768 B

  const int tid = threadIdx.x;
  const int lane = tid & 63;
  const int wave = tid >> 6;        // 0..7
  const int wm = wave >> 2;         // 0..1  -> 128-row half
  const int wn = wave & 3;          // 0..3  -> 32-col quarter
  // XCD-chunked swizzle: XCD k owns a 4(n) x 8(m) tile rectangle.
  const int bid0 = blockIdx.y * 8 + blockIdx.x;
  const int xk = bid0 & 7, xj = bid0 >> 3;
  const int m0 = ((xk >> 1) * 8 + (xj >> 2)) * 256;
  const int n0 = ((xk & 1) * 4 + (xj & 3)) * 128;
  const int fr = lane & 15;
  const int lch = lane >> 4;        // logical 16B chunk (k-group)

  // --- staging sources (pre-swizzled global addresses; LDS dest linear) ---
  const int gA0 = tid;              // A granules: tid, tid+512  (1024 x 16B)
  const int gA1 = tid + 512;
  const int rA0 = gA0 >> 2, lcA0 = (gA0 & 3) ^ ((rA0 >> 1) & 3);
  const int rA1 = gA1 >> 2, lcA1 = (gA1 & 3) ^ ((rA1 >> 1) & 3);
  const int rB = tid >> 2, lcB = (tid & 3) ^ ((rB >> 1) & 3);
  const f16_t* aSrc0 = Ag + (size_t)(m0 + rA0) * K + lcA0 * 8;
  const f16_t* aSrc1 = Ag + (size_t)(m0 + rA1) * K + lcA1 * 8;
  const f16_t* bhSrc = BhG + (size_t)(n0 + rB) * K + lcB * 8;
  const f16_t* blSrc = BlG + (size_t)(n0 + rB) * K + lcB * 8;
  char* ldsA0 = smem + gA0 * 16;
  char* ldsA1 = smem + gA1 * 16;
  char* ldsBh = smem + 16384 + (size_t)tid * 16;
  char* ldsBl = smem + 24576 + (size_t)tid * 16;

  // --- swizzled read offsets; per-slot LDS byte addresses (named scalars) ---
  const int swz = (lch ^ ((fr >> 1) & 3)) * 16;
  const int aoff = (wm * 128 + fr) * 64 + swz;
  const int boff = (wn * 32 + fr) * 64 + swz;
  const unsigned ldsBase =
      (unsigned)(size_t)(__attribute__((address_space(3))) char*)smem;
  const unsigned aA0 = ldsBase + (unsigned)aoff;
  const unsigned aA1 = aA0 + 32768u;
  const unsigned aA2 = aA0 + 65536u;
  const unsigned aA3 = aA0 + 98304u;
  const unsigned bA0 = ldsBase + 16384u + (unsigned)boff;
  const unsigned bA1 = bA0 + 32768u;
  const unsigned bA2 = bA0 + 65536u;
  const unsigned bA3 = bA0 + 98304u;

  floatx4 acc[8][2] = {};
  const int NS = K >> 5;            // 96 subtiles (multiple of 4)

#define STAGE(SS_, SLOT_)                                     \
  do {                                                        \
    int ss = (SS_); if (ss >= NS) ss -= NS;                   \
    const int k0 = ss * 32;                                   \
    async_copy16(aSrc0 + k0, ldsA0 + (SLOT_) * 32768);        \
    async_copy16(aSrc1 + k0, ldsA1 + (SLOT_) * 32768);        \
    async_copy16(bhSrc + k0, ldsBh + (SLOT_) * 32768);        \
    async_copy16(blSrc + k0, ldsBl + (SLOT_) * 32768);        \
  } while (0)

#define MFMA8(F_, P_)                                                                                               \
  do {                                                                                                              \
    acc[2*(P_)][0]   = __builtin_amdgcn_mfma_f32_16x16x32_f16((F_).a[2*(P_)],   (F_).bh0, acc[2*(P_)][0],   0,0,0); \
    acc[2*(P_)][1]   = __builtin_amdgcn_mfma_f32_16x16x32_f16((F_).a[2*(P_)],   (F_).bh1, acc[2*(P_)][1],   0,0,0); \
    acc[2*(P_)+1][0] = __builtin_amdgcn_mfma_f32_16x16x32_f16((F_).a[2*(P_)+1], (F_).bh0, acc[2*(P_)+1][0], 0,0,0); \
    acc[2*(P_)+1][1] = __builtin_amdgcn_mfma_f32_16x16x32_f16((F_).a[2*(P_)+1], (F_).bh1, acc[2*(P_)+1][1], 0,0,0); \
    acc[2*(P_)][0]   = __builtin_amdgcn_mfma_f32_16x16x32_f16((F_).a[2*(P_)],   (F_).bl0, acc[2*(P_)][0],   0,0,0); \
    acc[2*(P_)][1]   = __builtin_amdgcn_mfma_f32_16x16x32_f16((F_).a[2*(P_)],   (F_).bl1, acc[2*(P_)][1],   0,0,0); \
    acc[2*(P_)+1][0] = __builtin_amdgcn_mfma_f32_16x16x32_f16((F_).a[2*(P_)+1], (F_).bl0, acc[2*(P_)+1][0], 0,0,0); \
    acc[2*(P_)+1][1] = __builtin_amdgcn_mfma_f32_16x16x32_f16((F_).a[2*(P_)+1], (F_).bl1, acc[2*(P_)+1][1], 0,0,0); \
  } while (0)

#define SB0 __builtin_amdgcn_sched_barrier(0)

#define HALF(SPRE_, SLOTPRE_, ARD_, BRD_, FRD_, FMM_)            \
  do {                                                           \
    STAGE(SPRE_, SLOTPRE_);                                      \
    asm volatile("s_waitcnt vmcnt(8)" ::: "memory");             \
    __builtin_amdgcn_s_barrier();                                \
    DSR(FRD_.bh0, BRD_, "0");                                    \
    DSR(FRD_.bh1, BRD_, "1024");                                 \
    DSR(FRD_.bl0, BRD_, "8192");                                 \
    SB0;                                                         \
    asm volatile("s_waitcnt lgkmcnt(3)" ::: "memory");           \
    SB0;                                                         \
    __builtin_amdgcn_s_setprio(1);                               \
    MFMA8(FMM_, 0);                                              \
    __builtin_amdgcn_s_setprio(0);                               \
    SB0;                                                         \
    DSR(FRD_.bl1, BRD_, "9216");                                 \
    DSR(FRD_.a[0], ARD_, "0");                                   \
    DSR(FRD_.a[1], ARD_, "1024");                                \
    SB0;                                                         \
    __builtin_amdgcn_s_setprio(1);                               \
    MFMA8(FMM_, 1);                                              \
    __builtin_amdgcn_s_setprio(0);                               \
    SB0;                                                         \
    DSR(FRD_.a[2], ARD_, "2048");                                \
    DSR(FRD_.a[3], ARD_, "3072");                                \
    DSR(FRD_.a[4], ARD_, "4096");                                \
    SB0;                                                         \
    __builtin_amdgcn_s_setprio(1);                               \
    MFMA8(FMM_, 2);                                              \
    __builtin_amdgcn_s_setprio(0);                               \
    SB0;                                                         \
    DSR(FRD_.a[5], ARD_, "5120");                                \
    DSR(FRD_.a[6], ARD_, "6144");                                \
    DSR(FRD_.a[7], ARD_, "7168");                                \
    SB0;                                                         \
    __builtin_amdgcn_s_setprio(1);                               \
    MFMA8(FMM_, 3);                                              \
    __builtin_amdgcn_s_setprio(0);                               \
    SB0;                                                         \
  } while (0)

  Frags f0, f1;

  // prologue: stage subtiles 0,1,2; read frags(0)
  STAGE(0, 0); STAGE(1, 1); STAGE(2, 2);
  asm volatile("s_waitcnt vmcnt(8)" ::: "memory");
  __builtin_amdgcn_s_barrier();
  read_frags_asm(aA0, bA0, f0);
  SB0;

  for (int s = 0; s < NS; s += 4) {
    HALF(s + 3, 3, aA1, bA1, f1, f0);   // read s+1, mfma s
    HALF(s + 4, 0, aA2, bA2, f0, f1);   // read s+2, mfma s+1
    HALF(s + 5, 1, aA3, bA3, f1, f0);   // read s+3, mfma s+2
    HALF(s + 6, 2, aA0, bA0, f0, f1);   // read s+4, mfma s+3
  }
  asm volatile("s_waitcnt vmcnt(0)" ::: "memory");
#undef HALF
#undef STAGE
#undef MFMA8

  // epilogue: v*cscale + bias, split-store hi/lo
  const int mr = (lane >> 4) * 4;
#pragma unroll
  for (int j = 0; j < 2; ++j) {
    const int n = n0 + wn * 32 + j * 16 + fr;
    const float bj = bias[n];
#pragma unroll
    for (int i = 0; i < 8; ++i) {
#pragma unroll
      for (int r = 0; r < 4; ++r) {
        const int m = m0 + wm * 128 + i * 16 + mr + r;
        float v = acc[i][j][r] * cscale + bj;
        f16_t h = hi_of(v);
        Chi[(size_t)m * N + n] = h;
        Clo[(size_t)m * N + n] = lo_of(v, h);
      }
    }
  }
}

// fragment set for one BK=32 granule of gemm2: 4 A + 4 Bh + 4 Bl
struct Frags2 {
  f16x8 a[4];
  f16x8 bh[4];
  f16x8 bl[4];
};

// ---------------------------------------------------------------------------
// gemm2_pipe: G = S S^T - 1e5 I, triangular tiles + mirror (R8, verified).
// 3-slot x 24KB ring (72KB LDS) -> 2 blocks/CU. R10: flat 288-block grid,
// batch = bid&7 pins each batch's 36 blocks to one XCD (S 4MB fits L2).
// ---------------------------------------------------------------------------
__global__ __launch_bounds__(256, 2) void gemm2_pipe(
    const f16_t* __restrict__ Sh, const f16_t* __restrict__ Sl,
    float* __restrict__ Gf)
{
  const int K = 1024, N = 1024;
  const int batch = blockIdx.x & 7;          // XCD = linear bid % 8 (m09)
  const long long bo = (long long)batch * (1024LL * 1024);
  const f16_t* Ahi = Sh + bo;
  const f16_t* Bhi = Sh + bo;
  const f16_t* Blo = Sl + bo;
  float* Cf = Gf + bo;

  __shared__ __align__(16) char smem[73728];  // 3 slots x 24576 B

  const int tid = threadIdx.x;
  const int lane = tid & 63;
  const int wave = tid >> 6;       // 0..3
  const int wm = wave >> 1, wn = wave & 1;

  // triangular pair mapping: idx -> (i >= j)
  int idx = blockIdx.x >> 3, ti = 0, accu = 0;
  while (accu + ti + 1 <= idx) { accu += ti + 1; ++ti; }
  const int m0 = ti * 128;
  const int n0 = (idx - accu) * 128;

  const int fr = lane & 15;
  const int lch = lane >> 4;

  // staging: per thread 6 x 16B granule-chunks (A 2, Bh 2, Bl 2)
  const int gA0 = tid, gA1 = tid + 256;
  const int rA0 = gA0 >> 2, cA0 = (gA0 & 3) ^ ((rA0 >> 1) & 3);
  const int rA1 = gA1 >> 2, cA1 = (gA1 & 3) ^ ((rA1 >> 1) & 3);
  const f16_t* aSr0 = Ahi + (size_t)(m0 + rA0) * K + cA0 * 8;
  const f16_t* aSr1 = Ahi + (size_t)(m0 + rA1) * K + cA1 * 8;
  const f16_t* hSr0 = Bhi + (size_t)(n0 + rA0) * K + cA0 * 8;
  const f16_t* hSr1 = Bhi + (size_t)(n0 + rA1) * K + cA1 * 8;
  const f16_t* lSr0 = Blo + (size_t)(n0 + rA0) * K + cA0 * 8;
  const f16_t* lSr1 = Blo + (size_t)(n0 + rA1) * K + cA1 * 8;
  char* dA0 = smem + gA0 * 16;
  char* dA1 = smem + gA1 * 16;
  char* dH0 = smem + 8192 + gA0 * 16;
  char* dH1 = smem + 8192 + gA1 * 16;
  char* dL0 = smem + 16384 + gA0 * 16;
  char* dL1 = smem + 16384 + gA1 * 16;

  // swizzled read offsets; per-slot LDS addresses
  const int swz16 = (lch ^ ((fr >> 1) & 3)) * 16;
  const int aoff = (wm * 64 + fr) * 64 + swz16;
  const int boff = (wn * 64 + fr) * 64 + swz16;
  const unsigned ldsBase =
      (unsigned)(size_t)(__attribute__((address_space(3))) char*)smem;
  const unsigned aT0 = ldsBase + (unsigned)aoff;
  const unsigned aT1 = aT0 + 24576u;
  const unsigned aT2 = aT0 + 49152u;
  const unsigned bT0 = ldsBase + 8192u + (unsigned)boff;
  const unsigned bT1 = bT0 + 24576u;
  const unsigned bT2 = bT0 + 49152u;

  floatx4 acc[4][4] = {};
  const int NS = 32;

#define STAGE2(SS_, SLOT_)                                    \
  do {                                                        \
    int ss = (SS_); if (ss >= NS) ss -= NS;                   \
    const int k0 = ss * 32;                                   \
    async_copy16(aSr0 + k0, dA0 + (SLOT_) * 24576);           \
    async_copy16(aSr1 + k0, dA1 + (SLOT_) * 24576);           \
    async_copy16(hSr0 + k0, dH0 + (SLOT_) * 24576);           \
    async_copy16(hSr1 + k0, dH1 + (SLOT_) * 24576);           \
    async_copy16(lSr0 + k0, dL0 + (SLOT_) * 24576);           \
    async_copy16(lSr1 + k0, dL1 + (SLOT_) * 24576);           \
  } while (0)

#define MFMA8_2(F_, P_)                                                                              \
  do {                                                                                               \
    acc[0][P_] = __builtin_amdgcn_mfma_f32_16x16x32_f16((F_).a[0], (F_).bh[P_], acc[0][P_], 0,0,0);  \
    acc[1][P_] = __builtin_amdgcn_mfma_f32_16x16x32_f16((F_).a[1], (F_).bh[P_], acc[1][P_], 0,0,0);  \
    acc[2][P_] = __builtin_amdgcn_mfma_f32_16x16x32_f16((F_).a[2], (F_).bh[P_], acc[2][P_], 0,0,0);  \
    acc[3][P_] = __builtin_amdgcn_mfma_f32_16x16x32_f16((F_).a[3], (F_).bh[P_], acc[3][P_], 0,0,0);  \
    acc[0][P_] = __builtin_amdgcn_mfma_f32_16x16x32_f16((F_).a[0], (F_).bl[P_], acc[0][P_], 0,0,0);  \
    acc[1][P_] = __builtin_amdgcn_mfma_f32_16x16x32_f16((F_).a[1], (F_).bl[P_], acc[1][P_], 0,0,0);  \
    acc[2][P_] = __builtin_amdgcn_mfma_f32_16x16x32_f16((F_).a[2], (F_).bl[P_], acc[2][P_], 0,0,0);  \
    acc[3][P_] = __builtin_amdgcn_mfma_f32_16x16x32_f16((F_).a[3], (F_).bl[P_], acc[3][P_], 0,0,0);  \
  } while (0)

#define SB0 __builtin_amdgcn_sched_barrier(0)

#define GR3(SPRE_, SLOTPRE_, ARD_, BRD_, FRD_, FMM_)             \
  do {                                                           \
    STAGE2(SPRE_, SLOTPRE_);                                     \
    asm volatile("s_waitcnt vmcnt(6)" ::: "memory");             \
    __builtin_amdgcn_s_barrier();                                \
    DSR(FRD_.bh[0], BRD_, "0");                                  \
    DSR(FRD_.bh[1], BRD_, "1024");                               \
    DSR(FRD_.bh[2], BRD_, "2048");                               \
    SB0;                                                         \
    asm volatile("s_waitcnt lgkmcnt(3)" ::: "memory");           \
    SB0;                                                         \
    __builtin_amdgcn_s_setprio(1);                               \
    MFMA8_2(FMM_, 0);                                            \
    __builtin_amdgcn_s_setprio(0);                               \
    SB0;                                                         \
    DSR(FRD_.bh[3], BRD_, "3072");                               \
    DSR(FRD_.bl[0], BRD_, "8192");                               \
    DSR(FRD_.bl[1], BRD_, "9216");                               \
    SB0;                                                         \
    __builtin_amdgcn_s_setprio(1);                               \
    MFMA8_2(FMM_, 1);                                            \
    __builtin_amdgcn_s_setprio(0);                               \
    SB0;                                                         \
    DSR(FRD_.bl[2], BRD_, "10240");                              \
    DSR(FRD_.bl[3], BRD_, "11264");                              \
    DSR(FRD_.a[0], ARD_, "0");                                   \
    SB0;                                                         \
    __builtin_amdgcn_s_setprio(1);                               \
    MFMA8_2(FMM_, 2);                                            \
    __builtin_amdgcn_s_setprio(0);                               \
    SB0;                                                         \
    DSR(FRD_.a[1], ARD_, "1024");                                \
    DSR(FRD_.a[2], ARD_, "2048");                                \
    DSR(FRD_.a[3], ARD_, "3072");                                \
    SB0;                                                         \
    __builtin_amdgcn_s_setprio(1);                               \
    MFMA8_2(FMM_, 3);                                            \
    __builtin_amdgcn_s_setprio(0);                               \
    SB0;                                                         \
  } while (0)

  Frags2 f0, f1;

  // prologue: stage granules 0,1; read frags(0) from slot 0
  STAGE2(0, 0); STAGE2(1, 1);
  asm volatile("s_waitcnt vmcnt(6)" ::: "memory");   // granule 0 landed
  __builtin_amdgcn_s_barrier();
  DSR(f0.bh[0], bT0, "0");
  DSR(f0.bh[1], bT0, "1024");
  DSR(f0.bh[2], bT0, "2048");
  DSR(f0.bh[3], bT0, "3072");
  DSR(f0.bl[0], bT0, "8192");
  DSR(f0.bl[1], bT0, "9216");
  DSR(f0.bl[2], bT0, "10240");
  DSR(f0.bl[3], bT0, "11264");
  DSR(f0.a[0], aT0, "0");
  DSR(f0.a[1], aT0, "1024");
  DSR(f0.a[2], aT0, "2048");
  DSR(f0.a[3], aT0, "3072");
  SB0;

  // main loop: granules 0..29 (period-6 slot/frag pattern, 5 iters)
  for (int s = 0; s < 30; s += 6) {
    GR3(s + 2, 2, aT1, bT1, f1, f0);   // g=s+0: read s+1(slot1), mfma s
    GR3(s + 3, 0, aT2, bT2, f0, f1);   // g=s+1: read s+2(slot2), mfma s+1
    GR3(s + 4, 1, aT0, bT0, f1, f0);   // g=s+2: read s+3(slot0), mfma s+2
    GR3(s + 5, 2, aT1, bT1, f0, f1);   // g=s+3: read s+4(slot1), mfma s+3
    GR3(s + 6, 0, aT2, bT2, f1, f0);   // g=s+4: read s+5(slot2), mfma s+4
    GR3(s + 7, 1, aT0, bT0, f0, f1);   // g=s+5: read s+6(slot0), mfma s+5
  }
  // epilogue: granule 30 in f0 (read at g=29); granule 31 staged (slot 1)
  asm volatile("s_waitcnt vmcnt(0)" ::: "memory");
  __builtin_amdgcn_s_barrier();
  DSR(f1.bh[0], bT1, "0");
  DSR(f1.bh[1], bT1, "1024");
  DSR(f1.bh[2], bT1, "2048");
  DSR(f1.bh[3], bT1, "3072");
  DSR(f1.bl[0], bT1, "8192");
  DSR(f1.bl[1], bT1, "9216");
  DSR(f1.bl[2], bT1, "10240");
  DSR(f1.bl[3], bT1, "11264");
  DSR(f1.a[0], aT1, "0");
  DSR(f1.a[1], aT1, "1024");
  DSR(f1.a[2], aT1, "2048");
  DSR(f1.a[3], aT1, "3072");
  SB0;
  asm volatile("s_waitcnt lgkmcnt(12)" ::: "memory");  // granule 30 reads done
  SB0;
  __builtin_amdgcn_s_setprio(1);
  MFMA8_2(f0, 0); MFMA8_2(f0, 1); MFMA8_2(f0, 2); MFMA8_2(f0, 3);
  __builtin_amdgcn_s_setprio(0);
  SB0;
  asm volatile("s_waitcnt lgkmcnt(0)" ::: "memory");
  SB0;
  __builtin_amdgcn_s_setprio(1);
  MFMA8_2(f1, 0); MFMA8_2(f1, 1); MFMA8_2(f1, 2); MFMA8_2(f1, 3);
  __builtin_amdgcn_s_setprio(0);
#undef GR3
#undef MFMA8_2
#undef STAGE2

  // epilogue: C write (-1e5 diag), then mirror for off-diag tiles
  const int mr = (lane >> 4) * 4;
#pragma unroll
  for (int j = 0; j < 4; ++j) {
    const int n = n0 + wn * 64 + j * 16 + fr;
#pragma unroll
    for (int i = 0; i < 4; ++i) {
#pragma unroll
      for (int r = 0; r < 4; ++r) {
        const int m = m0 + wm * 64 + i * 16 + mr + r;
        float v = acc[i][j][r];
        if (m == n) v -= 1e5f;
        Cf[(size_t)m * N + n] = v;
      }
    }
  }

  if (m0 != n0) {
    float* T = (float*)smem;            // 128 x (stride 36) fp32 = 18432 B
#pragma unroll
    for (int mc = 0; mc < 4; ++mc) {    // 32-wide m-local chunks
      __syncthreads();
      if (wm == (mc >> 1)) {
        const int ibase = (mc & 1) * 2;
#pragma unroll
        for (int di = 0; di < 2; ++di) {
#pragma unroll
          for (int j = 0; j < 4; ++j) {
            const int nl = wn * 64 + j * 16 + fr;       // local col
#pragma unroll
            for (int r = 0; r < 4; ++r) {
              const int mloc = di * 16 + mr + r;        // within chunk
              T[nl * 36 + mloc] = acc[ibase + di][j][r];
            }
          }
        }
      }
      __syncthreads();
      const int row = tid >> 1, half = tid & 1;
      const float* src = &T[row * 36 + half * 16];
      float* dst = Cf + (size_t)(n0 + row) * N + m0 + mc * 32 + half * 16;
#pragma unroll
      for (int q = 0; q < 16; ++q) dst[q] = src[q];
    }
  }
}

// per-row max and 1/sum(exp(g-max)) of G; 4 rows per block (ILP)
__global__ __launch_bounds__(256) void rowstats_kernel(
    const float* __restrict__ G, float* __restrict__ mx, float* __restrict__ inv)
{
  __shared__ float redm[4][4], reds[4][4], mxsh[4];
  const int tid = threadIdx.x;
  const int r0 = blockIdx.x * 4;
  const float* g = G + (size_t)r0 * 1024;
  const float4 v0 = ((const float4*)g)[tid];
  const float4 v1 = ((const float4*)(g + 1024))[tid];
  const float4 v2 = ((const float4*)(g + 2048))[tid];
  const float4 v3 = ((const float4*)(g + 3072))[tid];

  float m0 = fmaxf(fmaxf(v0.x, v0.y), fmaxf(v0.z, v0.w));
  float m1 = fmaxf(fmaxf(v1.x, v1.y), fmaxf(v1.z, v1.w));
  float m2 = fmaxf(fmaxf(v2.x, v2.y), fmaxf(v2.z, v2.w));
  float m3 = fmaxf(fmaxf(v3.x, v3.y), fmaxf(v3.z, v3.w));
#pragma unroll
  for (int off = 32; off > 0; off >>= 1) {
    m0 = fmaxf(m0, __shfl_down(m0, off));
    m1 = fmaxf(m1, __shfl_down(m1, off));
    m2 = fmaxf(m2, __shfl_down(m2, off));
    m3 = fmaxf(m3, __shfl_down(m3, off));
  }
  if ((tid & 63) == 0) {
    redm[0][tid >> 6] = m0; redm[1][tid >> 6] = m1;
    redm[2][tid >> 6] = m2; redm[3][tid >> 6] = m3;
  }
  __syncthreads();
  if (tid < 4)
    mxsh[tid] = fmaxf(fmaxf(redm[tid][0], redm[tid][1]),
                      fmaxf(redm[tid][2], redm[tid][3]));
  __syncthreads();
  const float M0 = mxsh[0], M1 = mxsh[1], M2 = mxsh[2], M3 = mxsh[3];

  float s0 = __expf(v0.x - M0) + __expf(v0.y - M0) + __expf(v0.z - M0) + __expf(v0.w - M0);
  float s1 = __expf(v1.x - M1) + __expf(v1.y - M1) + __expf(v1.z - M1) + __expf(v1.w - M1);
  float s2 = __expf(v2.x - M2) + __expf(v2.y - M2) + __expf(v2.z - M2) + __expf(v2.w - M2);
  float s3 = __expf(v3.x - M3) + __expf(v3.y - M3) + __expf(v3.z - M3) + __expf(v3.w - M3);
#pragma unroll
  for (int off = 32; off > 0; off >>= 1) {
    s0 += __shfl_down(s0, off);
    s1 += __shfl_down(s1, off);
    s2 += __shfl_down(s2, off);
    s3 += __shfl_down(s3, off);
  }
  if ((tid & 63) == 0) {
    reds[0][tid >> 6] = s0; reds[1][tid >> 6] = s1;
    reds[2][tid >> 6] = s2; reds[3][tid >> 6] = s3;
  }
  __syncthreads();
  if (tid < 4) {
    mx[r0 + tid] = mxsh[tid];
    inv[r0 + tid] = 1.0f /
        (reds[tid][0] + reds[tid][1] + reds[tid][2] + reds[tid][3]);
  }
}

// At[l][m] = exp(G[l][m] - mx[m]) * inv[m]; 4 rows per block (ILP)
__global__ __launch_bounds__(256) void make_at_kernel(
    const float* __restrict__ G, const float* __restrict__ mx,
    const float* __restrict__ inv, f16_t* __restrict__ At)
{
  const int r0 = blockIdx.x * 4;
  const int b = r0 >> 10;
  const int tid = threadIdx.x;
  const float4 m = ((const float4*)(mx + b * 1024))[tid];
  const float4 iv = ((const float4*)(inv + b * 1024))[tid];
#pragma unroll
  for (int k = 0; k < 4; ++k) {
    const float4 g = ((const float4*)(G + (size_t)(r0 + k) * 1024))[tid];
    f16x4 o;
    o[0] = (f16_t)(__expf(g.x - m.x) * iv.x);
    o[1] = (f16_t)(__expf(g.y - m.y) * iv.y);
    o[2] = (f16_t)(__expf(g.z - m.z) * iv.z);
    o[3] = (f16_t)(__expf(g.w - m.w) * iv.w);
    *(f16x4*)(At + (size_t)(r0 + k) * 1024 + tid * 4) = o;
  }
}

// ---------------------------------------------------------------------------
// make_db split (R8): 128 blocks each. See R8 notes.
// ---------------------------------------------------------------------------
__global__ __launch_bounds__(256) void db_stats(
    const float* __restrict__ sup, float* __restrict__ colpart,
    float* __restrict__ totalpart)
{
  const int b = blockIdx.x >> 4, chunk = blockIdx.x & 15;
  const int tid = threadIdx.x;
  const int r = tid >> 2, q = tid & 3;
  const float* s = sup + ((size_t)b * 1024 + chunk * 64 + r) * 64 + q * 16;
  const float4 x0 = ((const float4*)s)[0];
  const float4 x1 = ((const float4*)s)[1];
  const float4 x2 = ((const float4*)s)[2];
  const float4 x3 = ((const float4*)s)[3];

  float rs = (x0.x + x0.y + x0.z + x0.w) + (x1.x + x1.y + x1.z + x1.w) +
             (x2.x + x2.y + x2.z + x2.w) + (x3.x + x3.y + x3.z + x3.w);
  rs += __shfl_xor(rs, 1);
  rs += __shfl_xor(rs, 2);
  const float rh = (rs > 0.5f) ? 1.f : 0.f;

  __shared__ float colp[64];
  __shared__ float tp[4];
  if (tid < 64) colp[tid] = 0.f;
  __syncthreads();
  atomicAdd(&colp[q * 16 + 0], x0.x);  atomicAdd(&colp[q * 16 + 1], x0.y);
  atomicAdd(&colp[q * 16 + 2], x0.z);  atomicAdd(&colp[q * 16 + 3], x0.w);
  atomicAdd(&colp[q * 16 + 4], x1.x);  atomicAdd(&colp[q * 16 + 5], x1.y);
  atomicAdd(&colp[q * 16 + 6], x1.z);  atomicAdd(&colp[q * 16 + 7], x1.w);
  atomicAdd(&colp[q * 16 + 8], x2.x);  atomicAdd(&colp[q * 16 + 9], x2.y);
  atomicAdd(&colp[q * 16 + 10], x2.z); atomicAdd(&colp[q * 16 + 11], x2.w);
  atomicAdd(&colp[q * 16 + 12], x3.x); atomicAdd(&colp[q * 16 + 13], x3.y);
  atomicAdd(&colp[q * 16 + 14], x3.z); atomicAdd(&colp[q * 16 + 15], x3.w);

  float ts = (q == 0) ? rh : 0.f;
#pragma unroll
  for (int off = 32; off > 0; off >>= 1) ts += __shfl_down(ts, off);
  if ((tid & 63) == 0) tp[tid >> 6] = ts;
  __syncthreads();
  if (tid < 64) colpart[((size_t)b * 16 + chunk) * 64 + tid] = colp[tid];
  if (tid == 0) totalpart[b * 16 + chunk] = tp[0] + tp[1] + tp[2] + tp[3];
}

__global__ __launch_bounds__(256) void db_apply(
    const float* __restrict__ sup, const float* __restrict__ colpart,
    const float* __restrict__ totalpart,
    float* __restrict__ Db, f16_t* __restrict__ DbT)
{
  const int b = blockIdx.x >> 4, chunk = blockIdx.x & 15;
  const int tid = threadIdx.x;
  const int r = tid >> 2, q = tid & 3;

  __shared__ float avgsh[64];
  __shared__ float totsh;
  __shared__ f16_t DbTs[64 * 72];

  float a = 0.f;
  if (tid < 64) {
#pragma unroll
    for (int c = 0; c < 16; ++c) a += colpart[((size_t)b * 16 + c) * 64 + tid];
  }
  if (tid == 0) {
    float tt = 0.f;
#pragma unroll
    for (int c = 0; c < 16; ++c) tt += totalpart[b * 16 + c];
    totsh = tt;
  }
  __syncthreads();
  if (tid < 64) avgsh[tid] = a / totsh;
  __syncthreads();

  const size_t rowoff = ((size_t)b * 1024 + chunk * 64 + r) * 64 + q * 16;
  const float* s = sup + rowoff;
  float4 x0 = ((const float4*)s)[0];
  float4 x1 = ((const float4*)s)[1];
  float4 x2 = ((const float4*)s)[2];
  float4 x3 = ((const float4*)s)[3];

  float rs = (x0.x + x0.y + x0.z + x0.w) + (x1.x + x1.y + x1.z + x1.w) +
             (x2.x + x2.y + x2.z + x2.w) + (x3.x + x3.y + x3.z + x3.w);
  rs += __shfl_xor(rs, 1);
  rs += __shfl_xor(rs, 2);
  const float rh = (rs > 0.5f) ? 1.f : 0.f;

  const int nb = q * 16;
  x0.x = (x0.x - avgsh[nb + 0]) * rh;  x0.y = (x0.y - avgsh[nb + 1]) * rh;
  x0.z = (x0.z - avgsh[nb + 2]) * rh;  x0.w = (x0.w - avgsh[nb + 3]) * rh;
  x1.x = (x1.x - avgsh[nb + 4]) * rh;  x1.y = (x1.y - avgsh[nb + 5]) * rh;
  x1.z = (x1.z - avgsh[nb + 6]) * rh;  x1.w = (x1.w - avgsh[nb + 7]) * rh;
  x2.x = (x2.x - avgsh[nb + 8]) * rh;  x2.y = (x2.y - avgsh[nb + 9]) * rh;
  x2.z = (x2.z - avgsh[nb + 10]) * rh; x2.w = (x2.w - avgsh[nb + 11]) * rh;
  x3.x = (x3.x - avgsh[nb + 12]) * rh; x3.y = (x3.y - avgsh[nb + 13]) * rh;
  x3.z = (x3.z - avgsh[nb + 14]) * rh; x3.w = (x3.w - avgsh[nb + 15]) * rh;

  float* d = Db + rowoff;
  ((float4*)d)[0] = x0; ((float4*)d)[1] = x1;
  ((float4*)d)[2] = x2; ((float4*)d)[3] = x3;

  DbTs[(nb + 0) * 72 + r] = (f16_t)x0.x;  DbTs[(nb + 1) * 72 + r] = (f16_t)x0.y;
  DbTs[(nb + 2) * 72 + r] = (f16_t)x0.z;  DbTs[(nb + 3) * 72 + r] = (f16_t)x0.w;
  DbTs[(nb + 4) * 72 + r] = (f16_t)x1.x;  DbTs[(nb + 5) * 72 + r] = (f16_t)x1.y;
  DbTs[(nb + 6) * 72 + r] = (f16_t)x1.z;  DbTs[(nb + 7) * 72 + r] = (f16_t)x1.w;
  DbTs[(nb + 8) * 72 + r] = (f16_t)x2.x;  DbTs[(nb + 9) * 72 + r] = (f16_t)x2.y;
  DbTs[(nb + 10) * 72 + r] = (f16_t)x2.z; DbTs[(nb + 11) * 72 + r] = (f16_t)x2.w;
  DbTs[(nb + 12) * 72 + r] = (f16_t)x3.x; DbTs[(nb + 13) * 72 + r] = (f16_t)x3.y;
  DbTs[(nb + 14) * 72 + r] = (f16_t)x3.z; DbTs[(nb + 15) * 72 + r] = (f16_t)x3.w;
  __syncthreads();

  // write DbT[n][chunk*64 + seg*16 ..): 16 f16 per thread, coalesced
  const int n = tid >> 2, seg = tid & 3;
  const f16_t* src = &DbTs[n * 72 + seg * 16];
  f16_t* dst = DbT + ((size_t)b * 64 + n) * 1024 + chunk * 64 + seg * 16;
  *(f16x8*)dst = *(const f16x8*)src;
  *(f16x8*)(dst + 8) = *(const f16x8*)(src + 8);
}

// ---------------------------------------------------------------------------
// Fused power-iteration step (R6): 256 blocks, 4 waves, private dbuf LDS
// per wave, reduce in old ks order -> bit-identical. R10: flat grid with
// batch = bid&7 -> batch's At (2MB) pinned to one XCD L2.
// ---------------------------------------------------------------------------
template <int PRED, int FINAL>
__global__ __launch_bounds__(256) void iter_step(
    const f16_t* __restrict__ At, const f16_t* __restrict__ UT,
    const float* __restrict__ Db, const float* __restrict__ Pred,
    f16_t* __restrict__ UTn, float* __restrict__ OutF)
{
  const int L = 1024, Nn = 64;
  const int b = blockIdx.x & 7, l0 = (blockIdx.x >> 3) * 32;
  At += (size_t)b * L * L;
  UT += (size_t)b * Nn * L;

  __shared__ __align__(16) char smem[131072];

  const int tid = threadIdx.x;
  const int lane = tid & 63;
  const int wave = tid >> 6;
  const int fr = lane & 15;
  const int lch = lane >> 4;
  const int mwb = wave * 256;       // wave's m-range base

  int g_, rw_, sc_;
  g_ = lane;        rw_ = g_ >> 3; sc_ = (g_ & 7) ^ (rw_ & 7);
  const f16_t* aS0 = At + (size_t)(l0 + rw_) * L + mwb + sc_ * 8;
  g_ = lane + 64;   rw_ = g_ >> 3; sc_ = (g_ & 7) ^ (rw_ & 7);
  const f16_t* aS1 = At + (size_t)(l0 + rw_) * L + mwb + sc_ * 8;
  g_ = lane + 128;  rw_ = g_ >> 3; sc_ = (g_ & 7) ^ (rw_ & 7);
  const f16_t* aS2 = At + (size_t)(l0 + rw_) * L + mwb + sc_ * 8;
  g_ = lane + 192;  rw_ = g_ >> 3; sc_ = (g_ & 7) ^ (rw_ & 7);
  const f16_t* aS3 = At + (size_t)(l0 + rw_) * L + mwb + sc_ * 8;
  g_ = lane;        rw_ = g_ >> 3; sc_ = (g_ & 7) ^ (rw_ & 7);
  const f16_t* uS0 = UT + (size_t)rw_ * L + mwb + sc_ * 8;
  g_ = lane + 64;   rw_ = g_ >> 3; sc_ = (g_ & 7) ^ (rw_ & 7);
  const f16_t* uS1 = UT + (size_t)rw_ * L + mwb + sc_ * 8;
  g_ = lane + 128;  rw_ = g_ >> 3; sc_ = (g_ & 7) ^ (rw_ & 7);
  const f16_t* uS2 = UT + (size_t)rw_ * L + mwb + sc_ * 8;
  g_ = lane + 192;  rw_ = g_ >> 3; sc_ = (g_ & 7) ^ (rw_ & 7);
  const f16_t* uS3 = UT + (size_t)rw_ * L + mwb + sc_ * 8;
  g_ = lane + 256;  rw_ = g_ >> 3; sc_ = (g_ & 7) ^ (rw_ & 7);
  const f16_t* uS4 = UT + (size_t)rw_ * L + mwb + sc_ * 8;
  g_ = lane + 320;  rw_ = g_ >> 3; sc_ = (g_ & 7) ^ (rw_ & 7);
  const f16_t* uS5 = UT + (size_t)rw_ * L + mwb + sc_ * 8;
  g_ = lane + 384;  rw_ = g_ >> 3; sc_ = (g_ & 7) ^ (rw_ & 7);
  const f16_t* uS6 = UT + (size_t)rw_ * L + mwb + sc_ * 8;
  g_ = lane + 448;  rw_ = g_ >> 3; sc_ = (g_ & 7) ^ (rw_ & 7);
  const f16_t* uS7 = UT + (size_t)rw_ * L + mwb + sc_ * 8;

  char* stA = smem + wave * 24576;          // buf c: +c*12288
  char* stU = stA + 4096;

  const int offK0 = fr * 128 + ((lch ^ (fr & 7)) * 16);
  const int offK1 = fr * 128 + (((4 + lch) ^ (fr & 7)) * 16);

  floatx4 acc[2][4] = {};

#define STG(M0_, BUF_)                                        \
  do {                                                        \
    char* dA = stA + (BUF_) * 12288;                          \
    char* dU = stU + (BUF_) * 12288;                          \
    async_copy16(aS0 + (M0_), dA + lane * 16);                \
    async_copy16(aS1 + (M0_), dA + 1024 + lane * 16);         \
    async_copy16(aS2 + (M0_), dA + 2048 + lane * 16);         \
    async_copy16(aS3 + (M0_), dA + 3072 + lane * 16);         \
    async_copy16(uS0 + (M0_), dU + lane * 16);                \
    async_copy16(uS1 + (M0_), dU + 1024 + lane * 16);         \
    async_copy16(uS2 + (M0_), dU + 2048 + lane * 16);         \
    async_copy16(uS3 + (M0_), dU + 3072 + lane * 16);         \
    async_copy16(uS4 + (M0_), dU + 4096 + lane * 16);         \
    async_copy16(uS5 + (M0_), dU + 5120 + lane * 16);         \
    async_copy16(uS6 + (M0_), dU + 6144 + lane * 16);         \
    async_copy16(uS7 + (M0_), dU + 7168 + lane * 16);         \
  } while (0)

#define LD8(b_, o_) (*(const f16x8*)((b_) + (o_)))
#define MM(A_, U_, C_) C_ = __builtin_amdgcn_mfma_f32_16x16x32_f16(A_, U_, C_, 0, 0, 0)

#define CHUNK(BUF_)                                                       \
  do {                                                                    \
    const char* cA = stA + (BUF_) * 12288;                                \
    const char* cU = stU + (BUF_) * 12288;                                \
    f16x8 a00 = LD8(cA, offK0), a01 = LD8(cA, offK1);                     \
    f16x8 a10 = LD8(cA, offK0 + 2048), a11 = LD8(cA, offK1 + 2048);       \
    f16x8 u00 = LD8(cU, offK0), u01 = LD8(cU, offK1);                     \
    f16x8 u10 = LD8(cU, offK0 + 2048), u11 = LD8(cU, offK1 + 2048);       \
    f16x8 u20 = LD8(cU, offK0 + 4096), u21 = LD8(cU, offK1 + 4096);       \
    f16x8 u30 = LD8(cU, offK0 + 6144), u31 = LD8(cU, offK1 + 6144);       \
    MM(a00, u00, acc[0][0]); MM(a00, u10, acc[0][1]);                     \
    MM(a00, u20, acc[0][2]); MM(a00, u30, acc[0][3]);                     \
    MM(a10, u00, acc[1][0]); MM(a10, u10, acc[1][1]);                     \
    MM(a10, u20, acc[1][2]); MM(a10, u30, acc[1][3]);                     \
    MM(a01, u01, acc[0][0]); MM(a01, u11, acc[0][1]);                     \
    MM(a01, u21, acc[0][2]); MM(a01, u31, acc[0][3]);                     \
    MM(a11, u01, acc[1][0]); MM(a11, u11, acc[1][1]);                     \
    MM(a11, u21, acc[1][2]); MM(a11, u31, acc[1][3]);                     \
  } while (0)

#define SB0 __builtin_amdgcn_sched_barrier(0)

  STG(0, 0);
  STG(64, 1);
  asm volatile("s_waitcnt vmcnt(12)" ::: "memory");
  SB0;
  CHUNK(0);
  SB0;
  STG(128, 0);
  asm volatile("s_waitcnt vmcnt(12)" ::: "memory");
  SB0;
  CHUNK(1);
  SB0;
  STG(192, 1);
  asm volatile("s_waitcnt vmcnt(12)" ::: "memory");
  SB0;
  CHUNK(0);
  SB0;
  asm volatile("s_waitcnt vmcnt(0)" ::: "memory");
  SB0;
  CHUNK(1);
#undef CHUNK
#undef STG

  // ---- reduce: write wave partials, then sum in old ks order ----
  float* P = (float*)(smem + 98304) + wave * 2048;    // 32x64 fp32
  const int mr = (lane >> 4) * 4;
#pragma unroll
  for (int li = 0; li < 2; ++li)
#pragma unroll
    for (int j = 0; j < 4; ++j)
#pragma unroll
      for (int r = 0; r < 4; ++r)
        P[(li * 16 + mr + r) * 64 + j * 16 + fr] = acc[li][j][r];
  __syncthreads();

  const float* P0 = (const float*)(smem + 98304);
  const size_t obase = ((size_t)b * L + l0) * Nn;
  f16_t* OutS = (f16_t*)smem;                         // 64 n x stride 40 f16
#pragma unroll
  for (int it = 0; it < 2; ++it) {
    const int e4 = it * 256 + tid;                    // 512 float4s
    const int l = e4 >> 4, n4 = (e4 & 15) * 4;
    const int eo = l * 64 + n4;
    float4 v = *(const float4*)(P0 + eo);
    const float4 p1 = *(const float4*)(P0 + 2048 + eo);
    const float4 p2 = *(const float4*)(P0 + 4096 + eo);
    const float4 p3 = *(const float4*)(P0 + 6144 + eo);
    v.x += p1.x; v.y += p1.y; v.z += p1.z; v.w += p1.w;
    v.x += p2.x; v.y += p2.y; v.z += p2.z; v.w += p2.w;
    v.x += p3.x; v.y += p3.y; v.z += p3.z; v.w += p3.w;
    const float4 d = *(const float4*)(Db + obase + eo);
    v.x += d.x; v.y += d.y; v.z += d.z; v.w += d.w;
    if (PRED) {
      const float4 p = *(const float4*)(Pred + obase + eo);
      v.x += p.x; v.y += p.y; v.z += p.z; v.w += p.w;
    }
    if (FINAL) {
      *(float4*)(OutF + obase + eo) = v;
    } else {
      OutS[(n4 + 0) * 40 + l] = (f16_t)v.x;
      OutS[(n4 + 1) * 40 + l] = (f16_t)v.y;
      OutS[(n4 + 2) * 40 + l] = (f16_t)v.z;
      OutS[(n4 + 3) * 40 + l] = (f16_t)v.w;
    }
  }
  if (!FINAL) {
    __syncthreads();
    f16_t* dst = UTn + (size_t)b * Nn * L + l0;
    const int n = tid >> 2, lc = (tid & 3) * 8;
    *(f16x8*)(dst + (size_t)n * L + lc) = *(const f16x8*)&OutS[n * 40 + lc];
  }
#undef SB0
#undef LD8
#undef MM
}

extern "C" void kernel_launch(void* const* d_in, const int* in_sizes, int n_in,
                              void* d_out, int out_size, void* d_ws, size_t ws_size,
                              hipStream_t stream) {
  const float* samples = (const float*)d_in[0];  // [8,1024,3072]
  const float* label   = (const float*)d_in[1];  // [8,1024,64]
  const float* predict = (const float*)d_in[2];  // [8,1024,64]
  const float* W       = (const float*)d_in[3];  // [1024,3072]
  const float* bproj   = (const float*)d_in[4];  // [1024]
  float* out = (float*)d_out;                    // [8,1024,64]

  char* ws = (char*)d_ws;
  // region A [0, 12.58 MB): Whi/Wlo during projection; small buffers after
  f16_t* Whi = (f16_t*)ws;
  f16_t* Wlo = (f16_t*)(ws + 6291456);
  float* mx  = (float*)ws;                       // after gemm1 (W dead)
  float* inv = (float*)(ws + 32768);
  float* Db  = (float*)(ws + 65536);             // 2 MB
  f16_t* DbT = (f16_t*)(ws + 65536 + 2097152);   // 1 MB
  f16_t* UTa = (f16_t*)(ws + 65536 + 3145728);   // 1 MB
  f16_t* UTb = (f16_t*)(ws + 65536 + 4194304);   // 1 MB
  float* colpart   = (float*)(ws + 5308416);     // 8x16x64 fp32 = 32 KB
  float* totalpart = (float*)(ws + 5308416 + 32768);  // 8x16 fp32
  // region B [12.58, 62.9 MB): SampH (50 MB) during gemm1; G (32 MB) after
  f16_t* SampH = (f16_t*)(ws + 12582912);
  float* G     = (float*)(ws + 12582912);
  // region C [62.9, 96.5 MB): Shi/Slo; At aliases Shi
  f16_t* Shi = (f16_t*)(ws + 62914560);
  f16_t* Slo = (f16_t*)(ws + 62914560 + 16777216);
  f16_t* At  = Shi;

  // 0) prep: W split + samples convert (fused)
  prep_kernel<<<dim3(27648), 256, 0, stream>>>(W, Whi, Wlo, samples, SampH);

  // 1) S = samples @ W^T + b; epilogue x(1/32)+bias, split-store hi/lo
  gemm1_pipe<<<dim3(8, 32), 512, 0, stream>>>(
      SampH, Whi, Wlo, bproj, Shi, Slo, 1024, 3072, 1.0f / 32.0f);

  // 2) G = S S^T - 1e5 I; flat 288 grid, batch = bid&7 -> XCD-pinned
  gemm2_pipe<<<dim3(288), 256, 0, stream>>>(Shi, Slo, G);

  // 3) row stats (4 rows/block), then At = softmax^T fp16 (4 rows/block)
  rowstats_kernel<<<2048, 256, 0, stream>>>(G, mx, inv);
  make_at_kernel<<<2048, 256, 0, stream>>>(G, mx, inv, At);

  // 4) Db fp32 + DbT fp16: stats partials + apply (128 blocks each)
  db_stats<<<128, 256, 0, stream>>>(label, colpart, totalpart);
  db_apply<<<128, 256, 0, stream>>>(label, colpart, totalpart, Db, DbT);

  // 5) power iteration: fused steps; flat 256 grid, batch = bid&7 XCD-pinned
  iter_step<0, 0><<<dim3(256), 256, 0, stream>>>(At, DbT, Db, nullptr, UTa, nullptr); // t=2
  iter_step<1, 0><<<dim3(256), 256, 0, stream>>>(At, UTa, Db, predict, UTb, nullptr); // t=3
  iter_step<0, 0><<<dim3(256), 256, 0, stream>>>(At, UTb, Db, nullptr, UTa, nullptr); // t=4
  iter_step<0, 0><<<dim3(256), 256, 0, stream>>>(At, UTa, Db, nullptr, UTb, nullptr); // t=5
  iter_step<0, 1><<<dim3(256), 256, 0, stream>>>(At, UTb, Db, nullptr, nullptr, out); // t=6
}